// Round 11
// baseline (484.046 us; speedup 1.0000x reference)
//
#include <hip/hip_runtime.h>
#include <math.h>
#include <stdint.h>

#define S 2048
#define HID 2048
#define NH 16
#define QL 1536
#define KVL 512
#define DN 128
#define DR 64
#define DV 128
#define DQ 192
#define IH 4
#define ID 128
#define TOPK 1024

#define N1 2244   // Wq_a(1536) | Wkv_a(576) | IWk(128) | IWproj(4)
#define N2 3584   // Wq_b(3072) | IWq_b(512)

// WTp sub-buffers (ushort elems): c2 Wq_b|IWq_b | Wkv_b^T | Wo^T | c1 block
#define WT_OFF3 ((size_t)N2 * QL)                    // 5505024
#define WT_OFF4 (WT_OFF3 + (size_t)4096 * KVL)       // 7602176
#define WT_OFF5 (WT_OFF4 + (size_t)2048 * 2048)      // 11796480
#define WT_TOTAL (WT_OFF5 + (size_t)N1 * HID)        // 16392192

#define CDIV(a,b) (((a)+(b)-1)/(b))

typedef float f32x4 __attribute__((ext_vector_type(4)));
typedef short bf16x8 __attribute__((ext_vector_type(8)));

__device__ __forceinline__ ushort f2b(float f) {
    uint32_t u = __float_as_uint(f);
    u += 0x7fffu + ((u >> 16) & 1u);
    return (ushort)(u >> 16);
}

#define GLL16(g, l)                                                            \
    __builtin_amdgcn_global_load_lds(                                          \
        (const __attribute__((address_space(1))) void*)(g),                    \
        (__attribute__((address_space(3))) void*)(l), 16, 0, 0)

// ============ GEMM tile body (R5/R7-proven structure, LDS passed in) =========
// 2-phase dbuf + BK=64 + rule-#21 swizzle. As/Bs: each 2*8192 ushorts (32KB).
// HALF=1 -> bf16 output. Inlined so addrspace inference recovers LDS for the
// ds_read/GLL16 paths (pointer chain visible from __shared__ in caller).
#define STG64T(k0, s)                                                          \
    {                                                                          \
        _Pragma("unroll")                                                      \
        for (int p = 0; p < 4; p++) {                                          \
            GLL16(pA[p] + (k0), As + (s) * 8192 + p * 2048 + doff);            \
            GLL16(pB[p] + (k0), Bs + (s) * 8192 + p * 2048 + doff);            \
        }                                                                      \
    }

template<int HALF>
__device__ __forceinline__ void gemm_tile(const ushort* __restrict__ A,
                                          const ushort* __restrict__ BT,
                                          void* __restrict__ Cv,
                                          int N, int K, int row0, int col0,
                                          ushort* As, ushort* Bs) {
    const int tid = threadIdx.x;
    const int w = tid >> 6, l = tid & 63;
    const int quad = l >> 4, lane = l & 15;
    const int wr = (w >> 1) * 64, wc = (w & 1) * 64;
    f32x4 acc[4][4];
#pragma unroll
    for (int i = 0; i < 4; i++)
#pragma unroll
        for (int j = 0; j < 4; j++) acc[i][j] = (f32x4)0.f;

    const int r32 = tid >> 3;                              // 0..31
    const int csw = (((tid & 7) ^ (r32 & 7)) * 8);         // ushort offset
    const ushort* pA[4];
    const ushort* pB[4];
#pragma unroll
    for (int p = 0; p < 4; p++) {
        pA[p] = A + (size_t)(row0 + p * 32 + r32) * K + csw;
        int bn = col0 + p * 32 + r32; if (bn > N - 1) bn = N - 1;
        pB[p] = BT + (size_t)bn * K + csw;
    }
    const int doff = r32 * 64 + (tid & 7) * 8;             // linear LDS dst

    const int nt = K >> 6;
    STG64T(0, 0);
    asm volatile("s_waitcnt vmcnt(0)" ::: "memory");
    __builtin_amdgcn_s_barrier();

    const int xsw = (lane & 7) << 3;                       // read-side XOR
    int cur = 0;
    for (int t = 0; t < nt; ++t) {
        if (t + 1 < nt) STG64T((t + 1) * 64, cur ^ 1);
#pragma unroll
        for (int kk = 0; kk < 2; kk++) {
            const int fo = (kk * 32 + quad * 8) ^ xsw;
            bf16x8 af[4], bf[4];
#pragma unroll
            for (int mi = 0; mi < 4; mi++)
                af[mi] = *(const bf16x8*)(As + cur * 8192 + (wr + mi * 16 + lane) * 64 + fo);
#pragma unroll
            for (int ni = 0; ni < 4; ni++)
                bf[ni] = *(const bf16x8*)(Bs + cur * 8192 + (wc + ni * 16 + lane) * 64 + fo);
#pragma unroll
            for (int mi = 0; mi < 4; mi++)
#pragma unroll
                for (int ni = 0; ni < 4; ni++)
                    acc[mi][ni] = __builtin_amdgcn_mfma_f32_16x16x32_bf16(af[mi], bf[ni], acc[mi][ni], 0, 0, 0);
        }
        asm volatile("s_waitcnt vmcnt(0)" ::: "memory");
        __builtin_amdgcn_s_barrier();
        cur ^= 1;
    }
#pragma unroll
    for (int mi = 0; mi < 4; mi++)
#pragma unroll
        for (int ni = 0; ni < 4; ni++)
#pragma unroll
            for (int r = 0; r < 4; r++) {
                int row = row0 + wr + mi * 16 + quad * 4 + r;
                int col = col0 + wc + ni * 16 + lane;
                if (col < N) {
                    if (HALF) ((ushort*)Cv)[(size_t)row * N + col] = f2b(acc[mi][ni][r]);
                    else      ((float*)Cv)[(size_t)row * N + col] = acc[mi][ni][r];
                }
            }
}

// ============ transpose body (LDS passed in; t = 64x65 f32 region) ===========
__device__ __forceinline__ void wtrans_lds(const float* W, ushort* WT, int K, int N,
                                           int k0, int n0, float* t) {
    int rr = threadIdx.x >> 6, cc = threadIdx.x & 63;
#pragma unroll
    for (int p = 0; p < 16; p++) {
        int k = k0 + p * 4 + rr, n = n0 + cc;
        t[(p * 4 + rr) * 65 + cc] = (k < K && n < N) ? W[(size_t)k * N + n] : 0.f;
    }
    __syncthreads();
#pragma unroll
    for (int p = 0; p < 16; p++) {
        int n = n0 + p * 4 + rr, k = k0 + cc;
        if (n < N && k < K) WT[(size_t)n * K + k] = f2b(t[cc * 65 + p * 4 + rr]);
    }
}

// ============ prep1: x->bf16 cvt + all 4 x-side weight transposes ============
// ids 0..1151 = transposes into the (de-aliased) c1 region; 1152..5247 = cvt.
__global__ __launch_bounds__(256) void prep1(const float* __restrict__ x,
                                             ushort* __restrict__ xb,
                                             const float* __restrict__ W0,
                                             const float* __restrict__ W1,
                                             const float* __restrict__ W2,
                                             const float* __restrict__ W3,
                                             ushort* __restrict__ WTc1) {
    __shared__ float tb[64 * 65];
    const int id = blockIdx.x;
    if (id < 1152) {
        const float* W; int N; size_t off; int loc;
        if (id < 768)       { W = W0; N = 1536; off = 0;                  loc = id; }
        else if (id < 1056) { W = W1; N = 576;  off = (size_t)1536 * HID; loc = id - 768; }
        else if (id < 1120) { W = W2; N = 128;  off = (size_t)2112 * HID; loc = id - 1056; }
        else                { W = W3; N = 4;    off = (size_t)2240 * HID; loc = id - 1120; }
        wtrans_lds(W, WTc1 + off, HID, N, (loc & 31) * 64, (loc >> 5) * 64, tb);
    } else {
        const int i = (id - 1152) * 256 + threadIdx.x;
        float4 v = *(const float4*)(x + (size_t)i * 4);
        uint32_t lo = (uint32_t)f2b(v.x) | ((uint32_t)f2b(v.y) << 16);
        uint32_t hi = (uint32_t)f2b(v.z) | ((uint32_t)f2b(v.w) << 16);
        *(uint2*)(xb + (size_t)i * 4) = make_uint2(lo, hi);
    }
}

// ============ megaC1: C1 GEMM (288 tiles, issued first) + prep2 transposes ===
// R10: C1 GEMM alone ran 288 blocks on 256 CUs (56% util, ~15us idle on 224
// CUs during round 2); prep2 (2880 transpose blocks) is fully independent ->
// merged so transposes fill the idle CUs. Transpose path reuses the first
// 16.6KB of the GEMM's 64KB LDS. c1 weights now live at WT_OFF5 (de-aliased
// from the Wq_b region prep2 writes concurrently).
__global__ __launch_bounds__(256) void megaC1(const ushort* __restrict__ xb,
                                              ushort* __restrict__ WT,
                                              float* __restrict__ C1,
                                              const float* __restrict__ Wq_b,
                                              const float* __restrict__ IWq_b,
                                              const float* __restrict__ Wkvb,
                                              const float* __restrict__ Wo) {
    __shared__ ushort As[2][8192];
    __shared__ ushort Bs[2][8192];
    const int id = blockIdx.x;
    if (id < 288) {
        gemm_tile<0>(xb, WT + WT_OFF5, C1, N1, HID, (id / 18) * 128, (id % 18) * 128,
                     &As[0][0], &Bs[0][0]);
    } else {
        const int pid = id - 288;
        const float* W; int K, N, nx; size_t off; int loc;
        if (pid < 1152)      { W = Wq_b;  K = QL;   N = 3072; nx = 24; off = 0;                 loc = pid; }
        else if (pid < 1344) { W = IWq_b; K = QL;   N = 512;  nx = 24; off = (size_t)3072 * QL; loc = pid - 1152; }
        else if (pid < 1856) { W = Wkvb;  K = KVL;  N = 4096; nx = 8;  off = WT_OFF3;           loc = pid - 1344; }
        else                 { W = Wo;    K = 2048; N = 2048; nx = 32; off = WT_OFF4;           loc = pid - 1856; }
        wtrans_lds(W, WT + off, K, N, (loc % nx) * 64, (loc / nx) * 64, (float*)&As[0][0]);
    }
}

// ============ megaC2: C2 GEMM (448) + kvexp GEMM (512) in one launch =========
// Independent after post_c1; merged grid 960 blocks = 3.75/CU (vs 1.75 + 2.0
// serial) -> ~9% of the two GEMMs' K-unit work saved + one launch gap.
__global__ __launch_bounds__(256) void megaC2(const ushort* __restrict__ qrb,
                                              const ushort* __restrict__ kvnb,
                                              const ushort* __restrict__ WT,
                                              float* __restrict__ C2,
                                              ushort* __restrict__ kvexp_h) {
    __shared__ ushort As[2][8192];
    __shared__ ushort Bs[2][8192];
    const int id = blockIdx.x;
    if (id < 448) {
        gemm_tile<0>(qrb, WT, C2, N2, QL, (id / 28) * 128, (id % 28) * 128,
                     &As[0][0], &Bs[0][0]);
    } else {
        const int loc = id - 448;
        gemm_tile<1>(kvnb, WT + WT_OFF3, kvexp_h, 4096, KVL,
                     (loc / 32) * 128, (loc % 32) * 128, &As[0][0], &Bs[0][0]);
    }
}

// ============ out GEMM (f32 out) =============================================
__global__ __launch_bounds__(256) void gemm_f32(const ushort* __restrict__ A,
                                                const ushort* __restrict__ BT,
                                                float* __restrict__ C,
                                                int N, int K) {
    __shared__ ushort As[2][8192];
    __shared__ ushort Bs[2][8192];
    gemm_tile<0>(A, BT, C, N, K, blockIdx.y * 128, blockIdx.x * 128,
                 &As[0][0], &Bs[0][0]);
}

// ============ fused post-C1: rmsnorm(qr), rmsnorm(kv), rope(kpe), LN+rope(ki)+T
__global__ __launch_bounds__(256) void post_c1(const float* __restrict__ C1,
                                               const float* __restrict__ qw,
                                               const float* __restrict__ kvw,
                                               const float* __restrict__ ikg,
                                               const float* __restrict__ ikb,
                                               const float* __restrict__ cosb,
                                               const float* __restrict__ sinb,
                                               ushort* __restrict__ qrb,
                                               ushort* __restrict__ kvnb,
                                               float* __restrict__ kpe,
                                               float* __restrict__ kiT) {
    const int t = blockIdx.x, tid = threadIdx.x;
    const float* row = C1 + (size_t)t * N1;
    __shared__ float red[256];
    __shared__ float kis[128];
    float ss = 0.f;
    for (int i = tid; i < 1536; i += 256) { float v = row[i]; ss += v * v; }
    red[tid] = ss; __syncthreads();
    for (int st = 128; st > 0; st >>= 1) { if (tid < st) red[tid] += red[tid + st]; __syncthreads(); }
    float sq = rsqrtf(red[0] / 1536.f + 1e-6f);
    __syncthreads();
    float s2 = 0.f;
    for (int i = tid; i < 512; i += 256) { float v = row[1536 + i]; s2 += v * v; }
    red[tid] = s2; __syncthreads();
    for (int st = 128; st > 0; st >>= 1) { if (tid < st) red[tid] += red[tid + st]; __syncthreads(); }
    float skv = rsqrtf(red[0] / 512.f + 1e-6f);
    __syncthreads();
    float kv_ = (tid < 128) ? row[2112 + tid] : 0.f;
    red[tid] = kv_; __syncthreads();
    for (int st = 128; st > 0; st >>= 1) { if (tid < st) red[tid] += red[tid + st]; __syncthreads(); }
    float mu = red[0] / 128.f;
    __syncthreads();
    red[tid] = kv_ * kv_; __syncthreads();
    for (int st = 128; st > 0; st >>= 1) { if (tid < st) red[tid] += red[tid + st]; __syncthreads(); }
    float var = red[0] / 128.f - mu * mu;
    for (int i = tid; i < 1536; i += 256) qrb[(size_t)t * QL + i] = f2b(row[i] * sq * qw[i]);
    for (int i = tid; i < 512; i += 256)  kvnb[(size_t)t * KVL + i] = f2b(row[1536 + i] * skv * kvw[i]);
    if (tid < 32) {
        float c = cosb[t * 32 + tid], s = sinb[t * 32 + tid];
        float xr = row[2048 + 2 * tid], xi = row[2048 + 2 * tid + 1];
        kpe[t * 64 + 2 * tid]     = xr * c - xi * s;
        kpe[t * 64 + 2 * tid + 1] = xr * s + xi * c;
    }
    if (tid < 128) kis[tid] = (kv_ - mu) * rsqrtf(var + 1e-6f) * ikg[tid] + ikb[tid];
    __syncthreads();
    if (tid < 128) {
        float outv;
        if (tid < 32) {
            float c = cosb[t * 32 + tid], s = sinb[t * 32 + tid];
            outv = kis[tid] * c - kis[tid + 32] * s;
        } else if (tid < 64) {
            int j = tid - 32;
            float c = cosb[t * 32 + j], s = sinb[t * 32 + j];
            outv = kis[j] * s + kis[tid] * c;
        } else {
            outv = kis[tid];
        }
        kiT[(size_t)tid * S + t] = outv;
    }
}

// ============ megaPost: post_c2 (2048) + pack_kv (512) in one launch =========
__global__ __launch_bounds__(256) void megaPost(float* __restrict__ C2,
                                                const float* __restrict__ cosb,
                                                const float* __restrict__ sinb,
                                                ushort* __restrict__ qb,
                                                const ushort* __restrict__ kvexp_h,
                                                const float* __restrict__ kpe,
                                                ushort* __restrict__ kb,
                                                ushort* __restrict__ vT) {
    __shared__ float cs[32], sn[32];
    __shared__ ushort tt[64][136];
    const int id = blockIdx.x, tid = threadIdx.x;
    if (id < 2048) {
        const int t = id;
        if (tid < 32) { cs[tid] = cosb[t * 32 + tid]; sn[tid] = sinb[t * 32 + tid]; }
        __syncthreads();
        const float sc = 0.10412775370051047f;  // 192^-0.5 * log2(e)
        const float* src0 = C2 + (size_t)t * N2;
        for (int i = tid; i < NH * 96; i += 256) {
            int h = i / 96, p = i % 96;
            const float* src = src0 + h * 192;
            ushort* dst = qb + ((size_t)h * S + t) * 192;
            if (p < 64) {
                dst[2 * p]     = f2b(src[2 * p] * sc);
                dst[2 * p + 1] = f2b(src[2 * p + 1] * sc);
            } else {
                int j = p - 64;
                float c = cs[j], s = sn[j];
                float xr = src[128 + 2 * j], xi = src[128 + 2 * j + 1];
                dst[128 + 2 * j]     = f2b((xr * c - xi * s) * sc);
                dst[128 + 2 * j + 1] = f2b((xr * s + xi * c) * sc);
            }
        }
        if (tid < 128) {
            int h = tid >> 5, j = tid & 31;
            float* p = C2 + (size_t)t * N2 + 3072 + h * 128;
            float c = cs[j], s = sn[j];
            float x1 = p[j], x2 = p[j + 32];
            p[j] = x1 * c - x2 * s;
            p[j + 32] = x1 * s + x2 * c;
        }
    } else {
        const int loc = id - 2048;
        const int s0 = (loc & 31) * 64, h = loc >> 5;
        const int row = tid >> 2, c = tid & 3;
        const ushort* src = kvexp_h + (size_t)(s0 + row) * 4096 + h * 256;
        ushort* kbr = kb + ((size_t)h * S + s0 + row) * 192;
#pragma unroll
        for (int i = 0; i < 4; i++) {
            int off = c * 32 + i * 8;
            *(uint4*)(kbr + off) = *(const uint4*)(src + off);
            *(uint4*)(&tt[row][off]) = *(const uint4*)(src + 128 + off);
        }
        const float* kp = kpe + (size_t)(s0 + row) * 64 + c * 16;
#pragma unroll
        for (int i = 0; i < 16; i++) kbr[128 + c * 16 + i] = f2b(kp[i]);
        __syncthreads();
        const int d = tid >> 1, sh = (tid & 1) * 32;
        ushort* dst = vT + ((size_t)h * 128 + d) * S + s0 + sh;
#pragma unroll
        for (int i = 0; i < 32; i++) dst[i] = tt[sh + i][d];
    }
}

// ============ indexer score, 4 t-rows per block (verified R6) ================
__global__ __launch_bounds__(256) void iscore4x4(const float* __restrict__ qi,
                                                 const float* __restrict__ kiT,
                                                 const float* __restrict__ iw,
                                                 float* __restrict__ iscore) {
    const int t0 = blockIdx.x * 4;
    const int s0 = blockIdx.y * 1024;
    if (s0 > t0 + 3) return;
    const int s = s0 + threadIdx.x * 4;
    __shared__ float qsT[4 * ID * 4];   // [h][d][tt]
    __shared__ float ws[16];            // [tt][h]
    for (int i = threadIdx.x; i < 4 * ID * 4; i += 256) {
        int tt = i & 3, hd = i >> 2;
        qsT[hd * 4 + tt] = qi[(size_t)(t0 + tt) * N2 + hd];
    }
    if (threadIdx.x < 16) {
        int tt = threadIdx.x >> 2, h = threadIdx.x & 3;
        ws[threadIdx.x] = iw[(size_t)(t0 + tt) * N1 + h] * 0.04419417382415922f;
    }
    __syncthreads();
    if (s > t0 + 3) return;
    float a[4][4][4];                   // [tt][h][c]
#pragma unroll
    for (int tt = 0; tt < 4; tt++)
#pragma unroll
        for (int h = 0; h < 4; h++)
#pragma unroll
            for (int c = 0; c < 4; c++) a[tt][h][c] = 0.f;
    for (int d = 0; d < ID; d++) {
        float4 kv = *(const float4*)(kiT + (size_t)d * S + s);
#pragma unroll
        for (int h = 0; h < 4; h++) {
            float4 qv = *(const float4*)(&qsT[(h * ID + d) * 4]);  // .x..w = tt 0..3
            a[0][h][0] += qv.x * kv.x; a[0][h][1] += qv.x * kv.y;
            a[0][h][2] += qv.x * kv.z; a[0][h][3] += qv.x * kv.w;
            a[1][h][0] += qv.y * kv.x; a[1][h][1] += qv.y * kv.y;
            a[1][h][2] += qv.y * kv.z; a[1][h][3] += qv.y * kv.w;
            a[2][h][0] += qv.z * kv.x; a[2][h][1] += qv.z * kv.y;
            a[2][h][2] += qv.z * kv.z; a[2][h][3] += qv.z * kv.w;
            a[3][h][0] += qv.w * kv.x; a[3][h][1] += qv.w * kv.y;
            a[3][h][2] += qv.w * kv.z; a[3][h][3] += qv.w * kv.w;
        }
    }
#pragma unroll
    for (int tt = 0; tt < 4; tt++) {
        const int t = t0 + tt;
        if (s > t) continue;
#pragma unroll
        for (int c = 0; c < 4; c++) {
            if (s + c > t) break;
            float sc = fmaxf(a[tt][0][c], 0.f) * ws[tt * 4 + 0] +
                       fmaxf(a[tt][1][c], 0.f) * ws[tt * 4 + 1] +
                       fmaxf(a[tt][2][c], 0.f) * ws[tt * 4 + 2] +
                       fmaxf(a[tt][3][c], 0.f) * ws[tt * 4 + 3];
            iscore[(size_t)t * S + s + c] = sc;
        }
    }
}

// ============ exact top-k -> bitmask (verified R6 shfl-scan version) =========
__device__ inline unsigned sortable_u32(float f) {
    unsigned u = __float_as_uint(f);
    return (u & 0x80000000u) ? ~u : (u | 0x80000000u);
}

__global__ __launch_bounds__(256) void topk_mask(const float* __restrict__ iscore,
                                                 uint32_t* __restrict__ msk) {
    int t = blockIdx.x, tid = threadIdx.x;
    uint32_t* mrow = msk + (size_t)t * 64;
    if (t < TOPK) {
        if (tid < 64) {
            int full = (t + 1) >> 5;
            uint32_t wv2 = (tid < full) ? 0xFFFFFFFFu : 0u;
            if (tid == full) { int rem = (t + 1) & 31; wv2 = rem ? ((1u << rem) - 1u) : 0u; }
            mrow[tid] = wv2;
        }
        return;
    }
    const float* row = iscore + (size_t)t * S;
    const int n = t + 1;
    const int wv = tid >> 6, lane = tid & 63;
    __shared__ int hist[4][256];
    __shared__ int wtot[4];
    __shared__ int bsel, ksel;
    __shared__ uint32_t bytes[256];

    int jb = tid * 8;
    float4 v0 = *(const float4*)(row + jb);
    float4 v1 = *(const float4*)(row + jb + 4);
    uint32_t lsu[8];
    {
        float vvv[8] = {v0.x, v0.y, v0.z, v0.w, v1.x, v1.y, v1.z, v1.w};
#pragma unroll
        for (int i = 0; i < 8; i++)
            lsu[i] = (jb + i < n) ? sortable_u32(vvv[i]) : 0u;
    }
    unsigned prefix = 0, prefmask = 0;
    int k = TOPK;
    for (int pass = 0; pass < 4; pass++) {
        int shift = 24 - pass * 8;
#pragma unroll
        for (int r = 0; r < 4; r++) hist[r][tid] = 0;
        __syncthreads();
#pragma unroll
        for (int i = 0; i < 8; i++) {
            uint32_t u = lsu[i];
            if ((u & prefmask) == prefix) atomicAdd(&hist[wv][(u >> shift) & 255], 1);
        }
        __syncthreads();
        int h = hist[0][tid] + hist[1][tid] + hist[2][tid] + hist[3][tid];
        // inclusive suffix sum over the 256 buckets: per-wave shfl + fixup
        int x = h;
#pragma unroll
        for (int off = 1; off < 64; off <<= 1) {
            int tmp = __shfl_down(x, off, 64);
            if (lane + off < 64) x += tmp;
        }
        if (lane == 0) wtot[wv] = x;           // wave total = suffix at lane 0
        __syncthreads();
        int add = 0;
#pragma unroll
        for (int w2 = 1; w2 < 4; w2++) if (w2 > wv) add += wtot[w2];
        x += add;                               // suffix over buckets tid..255
        int snext = x - h;                      // = suffix at tid+1 (0 at 255)
        if (x >= k && snext < k) { bsel = tid; ksel = k - snext; }
        __syncthreads();
        prefix |= ((unsigned)bsel) << shift;
        prefmask |= 0xFFu << shift;
        k = ksel;
        __syncthreads();
    }
    const unsigned u_thr = prefix;
    const int need = k;
    uint32_t gtbits = 0, eqbits = 0;
    int eqcnt = 0;
#pragma unroll
    for (int i = 0; i < 8; i++) {
        uint32_t u = lsu[i];
        if (u > u_thr) gtbits |= 1u << i;
        else if (u == u_thr) { eqbits |= 1u << i; eqcnt++; }
    }
    // inclusive prefix sum of eqcnt: per-wave shfl_up + fixup
    {
        int x = eqcnt;
#pragma unroll
        for (int off = 1; off < 64; off <<= 1) {
            int tmp = __shfl_up(x, off, 64);
            if (lane >= off) x += tmp;
        }
        if (lane == 63) wtot[wv] = x;          // wave total = prefix at lane 63
        __syncthreads();
        int add = 0;
#pragma unroll
        for (int w2 = 0; w2 < 3; w2++) if (w2 < wv) add += wtot[w2];
        x += add;                               // inclusive prefix over 256
        int room = need - (x - eqcnt);
        uint32_t keep = 0;
#pragma unroll
        for (int i = 0; i < 8; i++)
            if ((eqbits >> i) & 1u) { if (room > 0) { keep |= 1u << i; room--; } }
        bytes[tid] = gtbits | keep;
    }
    __syncthreads();
    if (tid < 64)
        mrow[tid] = bytes[tid * 4] | (bytes[tid * 4 + 1] << 8) |
                    (bytes[tid * 4 + 2] << 16) | (bytes[tid * 4 + 3] << 24);
}

// ============ split-K flash attention v10 (R7/R10-best ~81us — frozen) =======
__global__ __launch_bounds__(256, 2) void fattn10(const ushort* __restrict__ qb,
                                                  const ushort* __restrict__ kb,
                                                  const ushort* __restrict__ vT,
                                                  const uint32_t* __restrict__ msk,
                                                  float* __restrict__ Opart,
                                                  float* __restrict__ mlbuf) {
    __shared__ ushort Ks[24 * 512];   // 24 KB
    __shared__ ushort Vs[16 * 512];   // 16 KB
    __shared__ ushort Pm[4][16 * 72]; // 9 KB
    const int tid = threadIdx.x;
    const int w = tid >> 6, l = tid & 63, quad = l >> 4, lane = l & 15;
    const int b = blockIdx.x;
    const int r8 = b & 7, j = b >> 3;
    const int h = r8 + 8 * (j & 1);
    const int idx = j >> 1;
    const int pair = idx & 15, part = idx >> 4;
    const int ta = pair, tb = 31 - pair, nA = ta + 1;
    const int vlo = part * 11, vhi = vlo + 11;
    const int qa0 = ta * 64, qb0 = tb * 64;

    bf16x8 qfa[6], qfb[6];
    {
        const ushort* qpa = qb + ((size_t)h * S + qa0 + w * 16 + lane) * 192;
        const ushort* qpb = qb + ((size_t)h * S + qb0 + w * 16 + lane) * 192;
#pragma unroll
        for (int ks = 0; ks < 6; ks++) {
            qfa[ks] = *(const bf16x8*)(qpa + ks * 32 + quad * 8);
            qfb[ks] = *(const bf16x8*)(qpb + ks * 32 + quad * 8);
        }
    }
    f32x4 oa[8], ob[8];
#pragma unroll
    for (int i = 0; i < 8; i++) { oa[i] = (f32x4)0.f; ob[i] = (f32x4)0.f; }
    float la[4], lb[4];
#pragma unroll
    for (int r = 0; r < 4; r++) { la[r] = 0.f; lb[r] = 0.f; }

    ushort* pw = &Pm[w][0];
    const ushort* kbase = kb + (size_t)h * S * 192;
    const ushort* vbase = vT + (size_t)h * 128 * S;

    for (int kt = 0; kt <= tb; kt++) {
        const int idxB = (kt <= ta) ? 2 * kt : kt + nA;
        const int hasA = (kt <= ta);
        const int idxA = 2 * kt + 1;
        const bool doB = (idxB >= vlo && idxB < vhi);
        const bool doA = hasA && (idxA >= vlo && idxA < vhi);
        if (!(doA || doB)) continue;           // block-uniform
        const int s0 = kt * 64;
        __syncthreads();
        // ---- DMA K: 24 issues (6/wave). issue i: ks=i>>2, kq=i&3; lane: quad,r15
#pragma unroll
        for (int ii = 0; ii < 6; ii++) {
            const int i = w * 6 + ii;
            const int ks = i >> 2, kq = i & 3;
            const ushort* src = kbase + (size_t)(s0 + kq * 16 + lane) * 192 + ks * 32 + quad * 8;
            GLL16(src, Ks + i * 512 + l * 8);
        }
        // ---- DMA V: 16 issues (4/wave). issue i: k2=i>>3, nt=i&7; lane: quad,d15
#pragma unroll
        for (int ii = 0; ii < 4; ii++) {
            const int i = w * 4 + ii;
            const int k2 = i >> 3, nt = i & 7;
            const ushort* src = vbase + (size_t)(nt * 16 + lane) * S + s0 + k2 * 32 + quad * 8;
            GLL16(src, Vs + i * 512 + l * 8);
        }
        __syncthreads();   // drains DMA

#pragma unroll
        for (int pass = 0; pass < 2; pass++) {
            if (pass == 0 && !doA) continue;
            if (pass == 1 && !doB) continue;
            const bf16x8* qf = (pass == 0) ? qfa : qfb;
            f32x4* oacc      = (pass == 0) ? oa : ob;
            float* ll        = (pass == 0) ? la : lb;
            const int q0t    = (pass == 0) ? qa0 : qb0;

            // QK^T (scores in log2e domain)
            f32x4 sc[4];
#pragma unroll
            for (int kq = 0; kq < 4; kq++) {
                sc[kq] = (f32x4)0.f;
#pragma unroll
                for (int ks = 0; ks < 6; ks++) {
                    bf16x8 bfr = *(const bf16x8*)(Ks + (ks * 4 + kq) * 512 + quad * 128 + lane * 8);
                    sc[kq] = __builtin_amdgcn_mfma_f32_16x16x32_bf16(qf[ks], bfr, sc[kq], 0, 0, 0);
                }
            }
            // mask words
            uint32_t w0[4], w1[4];
            {
                const int rowbase = q0t + w * 16 + quad * 4;
#pragma unroll
                for (int r = 0; r < 4; r++) {
                    const uint32_t* mp = msk + (size_t)(rowbase + r) * 64 + (s0 >> 5);
                    w0[r] = mp[0]; w1[r] = mp[1];
                }
            }
            // max-free softmax body: e = exp2(v); masked v=-1e30 -> e = 0
#pragma unroll
            for (int kq = 0; kq < 4; kq++) {
                const int sh = (kq & 1) * 16 + lane;
#pragma unroll
                for (int r = 0; r < 4; r++) {
                    uint32_t word = (kq < 2) ? w0[r] : w1[r];
                    float v = ((word >> sh) & 1u) ? sc[kq][r] : -1e30f;
                    float e = exp2f(v);
                    ll[r] += e;                     // lane-local partial l
                    pw[(quad * 4 + r) * 72 + kq * 16 + lane] = f2b(e);
                }
            }

            bf16x8 pfr[2];
#pragma unroll
            for (int k2 = 0; k2 < 2; k2++)
                pfr[k2] = *(const bf16x8*)(pw + lane * 72 + k2 * 32 + quad * 8);
#pragma unroll
            for (int nt = 0; nt < 8; nt++) {
#pragma unroll
                for (int k2 = 0; k2 < 2; k2++) {
                    bf16x8 vfr = *(const bf16x8*)(Vs + ((k2 * 8 + nt) * 4 + quad) * 128 + lane * 8);
                    oacc[nt] = __builtin_amdgcn_mfma_f32_16x16x32_bf16(pfr[k2], vfr, oacc[nt], 0, 0, 0);
                }
            }
        }
    }
    // deferred cross-lane reduction of l (once per block; offs 1,2,4,8 stay
    // within each 16-lane group = the score-row's column owners)
#pragma unroll
    for (int off = 1; off < 16; off <<= 1)
#pragma unroll
        for (int r = 0; r < 4; r++) {
            la[r] += __shfl_xor(la[r], off, 64);
            lb[r] += __shfl_xor(lb[r], off, 64);
        }
    // epilogue: f32 partials (unnormalized O + m=0,l), 3 parts
#pragma unroll
    for (int pass = 0; pass < 2; pass++) {
        const f32x4* oacc = (pass == 0) ? oa : ob;
        const float* ll   = (pass == 0) ? la : lb;
        const int qt      = (pass == 0) ? ta : tb;
        float* Op = Opart + (size_t)((qt * 16 + h) * 3 + part) * (64 * 128);
        float* mlp = mlbuf + (size_t)((qt * 16 + h) * 3 + part) * 128;
#pragma unroll
        for (int nt = 0; nt < 8; nt++)
#pragma unroll
            for (int r = 0; r < 4; r++)
                Op[(w * 16 + quad * 4 + r) * 128 + nt * 16 + lane] = oacc[nt][r];
        if (lane == 0) {
#pragma unroll
            for (int r = 0; r < 4; r++) {
                mlp[(w * 16 + quad * 4 + r) * 2 + 0] = 0.f;
                mlp[(w * 16 + quad * 4 + r) * 2 + 1] = ll[r];
            }
        }
    }
}

// ============ combine 3 split-K partials -> attn_b bf16 ======================
__global__ __launch_bounds__(256) void attn_combine(const float* __restrict__ Opart,
                                                    const float* __restrict__ mlbuf,
                                                    ushort* __restrict__ attn_b) {
    const int qt = blockIdx.x, h = blockIdx.y, tid = threadIdx.x;
    const size_t base = ((size_t)qt * 16 + h) * 3;
    const float* Op0 = Opart + base * 8192;
    const float* Op1 = Op0 + 8192;
    const float* Op2 = Op1 + 8192;
    const float* ml0 = mlbuf + base * 128;
    const float* ml1 = ml0 + 128;
    const float* ml2 = ml1 + 128;
#pragma unroll
    for (int i = 0; i < 32; i++) {
        int id = tid + i * 256;
        int row = id >> 7, d = id & 127;
        float m0 = ml0[row * 2], l0 = ml0[row * 2 + 1];
        float m1 = ml1[row * 2], l1 = ml1[row * 2 + 1];
        float m2 = ml2[row * 2], l2 = ml2[row * 2 + 1];
        float m = fmaxf(fmaxf(m0, m1), m2);
        float e0 = exp2f(m0 - m), e1 = exp2f(m1 - m), e2 = exp2f(m2 - m);
        float linv = 1.f / (l0 * e0 + l1 * e1 + l2 * e2);
        float v = (Op0[id] * e0 + Op1[id] * e1 + Op2[id] * e2) * linv;
        attn_b[(size_t)(qt * 64 + row) * 2048 + h * 128 + d] = f2b(v);
    }
}

// ============ host ===========================================================
extern "C" void kernel_launch(void* const* d_in, const int* in_sizes, int n_in,
                              void* d_out, int out_size, void* d_ws, size_t ws_size,
                              hipStream_t stream) {
    const float* x        = (const float*)d_in[0];
    const float* cosb     = (const float*)d_in[1];
    const float* sinb     = (const float*)d_in[2];
    const float* Wq_a     = (const float*)d_in[4];
    const float* q_norm_w = (const float*)d_in[5];
    const float* Wq_b     = (const float*)d_in[6];
    const float* Wkv_a    = (const float*)d_in[7];
    const float* kv_norm_w= (const float*)d_in[8];
    const float* Wkv_b    = (const float*)d_in[9];
    const float* Wo       = (const float*)d_in[10];
    const float* IWq_b    = (const float*)d_in[11];
    const float* IWk      = (const float*)d_in[12];
    const float* Ik_norm_w= (const float*)d_in[13];
    const float* Ik_norm_b= (const float*)d_in[14];
    const float* IWproj   = (const float*)d_in[15];
    float* out = (float*)d_out;

    char* ws = (char*)d_ws;
    size_t o = 0;
    auto take = [&](size_t b) { char* p = ws + o; o += (b + 255) & ~(size_t)255; return p; };
    ushort* xb     = (ushort*)take((size_t)S * HID * 2);
    ushort* qrb    = (ushort*)take((size_t)S * QL * 2);
    ushort* qb     = (ushort*)take((size_t)NH * S * DQ * 2);
    ushort* kvnb   = (ushort*)take((size_t)S * KVL * 2);
    float*  kpe    = (float*)take((size_t)S * DR * 4);
    ushort* kb     = (ushort*)take((size_t)NH * S * DQ * 2);
    ushort* vT     = (ushort*)take((size_t)NH * DV * S * 2);
    uint32_t* msk  = (uint32_t*)take((size_t)S * 64 * 4);
    float*  mlbuf  = (float*)take((size_t)32 * 16 * 3 * 64 * 2 * 4);
    ushort* WTp    = (ushort*)take(WT_TOTAL * 2);                   // c2 | Wkv_b^T | Wo^T | c1
    float*  C1     = (float*)take((size_t)S * N1 * 4);
    char*   big    = take((size_t)32 * 16 * 3 * 8192 * 4 + 1024);   // C2 f32 then Opart
    ushort* kvexp_h= (ushort*)take((size_t)S * 4096 * 2);
    float*  kiT    = (float*)take((size_t)128 * S * 4);
    char*   poolb  = take((size_t)16777216);                        // iscore / attn_b

    float* C2     = (float*)big;              // [S][N2] (qi consumed by iscore)
    float* Opart  = (float*)big;              // [32][16][3][64][128] f32
    float* iscore = (float*)poolb;
    ushort* attn_b = (ushort*)poolb;          // after topk consumed iscore

    // --- prep1: x->bf16 + c1-region weight transposes (one launch)
    prep1<<<5248, 256, 0, stream>>>(x, xb, Wq_a, Wkv_a, IWk, IWproj, WTp + WT_OFF5);

    // --- megaC1: C1 GEMM + all remaining weight transposes (one launch)
    megaC1<<<3168, 256, 0, stream>>>(xb, WTp, C1, Wq_b, IWq_b, Wkv_b, Wo);
    post_c1<<<S, 256, 0, stream>>>(C1, q_norm_w, kv_norm_w, Ik_norm_w, Ik_norm_b,
                                   cosb, sinb, qrb, kvnb, kpe, kiT);

    // --- megaC2: C2 GEMM + kvexp GEMM (one launch)
    megaC2<<<960, 256, 0, stream>>>(qrb, kvnb, WTp, C2, kvexp_h);

    // --- megaPost: post_c2 + pack_kv (one launch)
    megaPost<<<2560, 256, 0, stream>>>(C2, cosb, sinb, qb, kvexp_h, kpe, kb, vT);

    // --- indexer scores + exact top-k -> bitmap
    iscore4x4<<<dim3(S / 4, S / 1024), 256, 0, stream>>>(C2 + 3072, kiT, C1 + 2240, iscore);
    topk_mask<<<S, 256, 0, stream>>>(iscore, msk);

    // --- split-K masked flash attention (3 parts) + combine
    fattn10<<<768, 256, 0, stream>>>(qb, kb, vT, msk, Opart, mlbuf);
    attn_combine<<<dim3(32, 16), 256, 0, stream>>>(Opart, mlbuf, attn_b);

    // --- out = attn @ Wo
    gemm_f32<<<dim3(HID / 128, S / 128), 256, 0, stream>>>(attn_b, WTp + WT_OFF4, out, HID, NH * DV);

    (void)in_sizes; (void)n_in; (void)out_size; (void)ws_size; (void)o;
}

// Round 12
// 462.669 us; speedup vs baseline: 1.0462x; 1.0462x over previous
//
#include <hip/hip_runtime.h>
#include <math.h>
#include <stdint.h>

#define S 2048
#define HID 2048
#define NH 16
#define QL 1536
#define KVL 512
#define DN 128
#define DR 64
#define DV 128
#define DQ 192
#define IH 4
#define ID 128
#define TOPK 1024

#define N1 2244   // Wq_a(1536) | Wkv_a(576) | IWk(128) | IWproj(4)
#define N2 3584   // Wq_b(3072) | IWq_b(512)

// WTp sub-buffers (ushort elems): c2 Wq_b|IWq_b | Wkv_b^T | Wo^T | c1 block
#define WT_OFF3 ((size_t)N2 * QL)                    // 5505024
#define WT_OFF4 (WT_OFF3 + (size_t)4096 * KVL)       // 7602176
#define WT_OFF5 (WT_OFF4 + (size_t)2048 * 2048)      // 11796480
#define WT_TOTAL (WT_OFF5 + (size_t)N1 * HID)        // 16392192

#define CDIV(a,b) (((a)+(b)-1)/(b))

typedef float f32x4 __attribute__((ext_vector_type(4)));
typedef short bf16x8 __attribute__((ext_vector_type(8)));

__device__ __forceinline__ ushort f2b(float f) {
    uint32_t u = __float_as_uint(f);
    u += 0x7fffu + ((u >> 16) & 1u);
    return (ushort)(u >> 16);
}

#define GLL16(g, l)                                                            \
    __builtin_amdgcn_global_load_lds(                                          \
        (const __attribute__((address_space(1))) void*)(g),                    \
        (__attribute__((address_space(3))) void*)(l), 16, 0, 0)

// ============ GEMM tile body (R5/R7-proven structure, LDS passed in) =========
// 2-phase dbuf + BK=64 + rule-#21 swizzle. As/Bs: each 2*8192 ushorts (32KB).
// HALF=1 -> bf16 output.
#define STG64T(k0, s)                                                          \
    {                                                                          \
        _Pragma("unroll")                                                      \
        for (int p = 0; p < 4; p++) {                                          \
            GLL16(pA[p] + (k0), As + (s) * 8192 + p * 2048 + doff);            \
            GLL16(pB[p] + (k0), Bs + (s) * 8192 + p * 2048 + doff);            \
        }                                                                      \
    }

template<int HALF>
__device__ __forceinline__ void gemm_tile(const ushort* __restrict__ A,
                                          const ushort* __restrict__ BT,
                                          void* __restrict__ Cv,
                                          int N, int K, int row0, int col0,
                                          ushort* As, ushort* Bs) {
    const int tid = threadIdx.x;
    const int w = tid >> 6, l = tid & 63;
    const int quad = l >> 4, lane = l & 15;
    const int wr = (w >> 1) * 64, wc = (w & 1) * 64;
    f32x4 acc[4][4];
#pragma unroll
    for (int i = 0; i < 4; i++)
#pragma unroll
        for (int j = 0; j < 4; j++) acc[i][j] = (f32x4)0.f;

    const int r32 = tid >> 3;                              // 0..31
    const int csw = (((tid & 7) ^ (r32 & 7)) * 8);         // ushort offset
    const ushort* pA[4];
    const ushort* pB[4];
#pragma unroll
    for (int p = 0; p < 4; p++) {
        pA[p] = A + (size_t)(row0 + p * 32 + r32) * K + csw;
        int bn = col0 + p * 32 + r32; if (bn > N - 1) bn = N - 1;
        pB[p] = BT + (size_t)bn * K + csw;
    }
    const int doff = r32 * 64 + (tid & 7) * 8;             // linear LDS dst

    const int nt = K >> 6;
    STG64T(0, 0);
    asm volatile("s_waitcnt vmcnt(0)" ::: "memory");
    __builtin_amdgcn_s_barrier();

    const int xsw = (lane & 7) << 3;                       // read-side XOR
    int cur = 0;
    for (int t = 0; t < nt; ++t) {
        if (t + 1 < nt) STG64T((t + 1) * 64, cur ^ 1);
#pragma unroll
        for (int kk = 0; kk < 2; kk++) {
            const int fo = (kk * 32 + quad * 8) ^ xsw;
            bf16x8 af[4], bf[4];
#pragma unroll
            for (int mi = 0; mi < 4; mi++)
                af[mi] = *(const bf16x8*)(As + cur * 8192 + (wr + mi * 16 + lane) * 64 + fo);
#pragma unroll
            for (int ni = 0; ni < 4; ni++)
                bf[ni] = *(const bf16x8*)(Bs + cur * 8192 + (wc + ni * 16 + lane) * 64 + fo);
#pragma unroll
            for (int mi = 0; mi < 4; mi++)
#pragma unroll
                for (int ni = 0; ni < 4; ni++)
                    acc[mi][ni] = __builtin_amdgcn_mfma_f32_16x16x32_bf16(af[mi], bf[ni], acc[mi][ni], 0, 0, 0);
        }
        asm volatile("s_waitcnt vmcnt(0)" ::: "memory");
        __builtin_amdgcn_s_barrier();
        cur ^= 1;
    }
#pragma unroll
    for (int mi = 0; mi < 4; mi++)
#pragma unroll
        for (int ni = 0; ni < 4; ni++)
#pragma unroll
            for (int r = 0; r < 4; r++) {
                int row = row0 + wr + mi * 16 + quad * 4 + r;
                int col = col0 + wc + ni * 16 + lane;
                if (col < N) {
                    if (HALF) ((ushort*)Cv)[(size_t)row * N + col] = f2b(acc[mi][ni][r]);
                    else      ((float*)Cv)[(size_t)row * N + col] = acc[mi][ni][r];
                }
            }
}

// ============ transpose body (LDS passed in; t = 64x65 f32 region) ===========
__device__ __forceinline__ void wtrans_lds(const float* W, ushort* WT, int K, int N,
                                           int k0, int n0, float* t) {
    int rr = threadIdx.x >> 6, cc = threadIdx.x & 63;
#pragma unroll
    for (int p = 0; p < 16; p++) {
        int k = k0 + p * 4 + rr, n = n0 + cc;
        t[(p * 4 + rr) * 65 + cc] = (k < K && n < N) ? W[(size_t)k * N + n] : 0.f;
    }
    __syncthreads();
#pragma unroll
    for (int p = 0; p < 16; p++) {
        int n = n0 + p * 4 + rr, k = k0 + cc;
        if (n < N && k < K) WT[(size_t)n * K + k] = f2b(t[cc * 65 + p * 4 + rr]);
    }
}

// ============ prep1: x->bf16 cvt + all 4 x-side weight transposes ============
// ids 0..1151 = transposes into the (de-aliased) c1 region; 1152..5247 = cvt.
__global__ __launch_bounds__(256) void prep1(const float* __restrict__ x,
                                             ushort* __restrict__ xb,
                                             const float* __restrict__ W0,
                                             const float* __restrict__ W1,
                                             const float* __restrict__ W2,
                                             const float* __restrict__ W3,
                                             ushort* __restrict__ WTc1) {
    __shared__ float tb[64 * 65];
    const int id = blockIdx.x;
    if (id < 1152) {
        const float* W; int N; size_t off; int loc;
        if (id < 768)       { W = W0; N = 1536; off = 0;                  loc = id; }
        else if (id < 1056) { W = W1; N = 576;  off = (size_t)1536 * HID; loc = id - 768; }
        else if (id < 1120) { W = W2; N = 128;  off = (size_t)2112 * HID; loc = id - 1056; }
        else                { W = W3; N = 4;    off = (size_t)2240 * HID; loc = id - 1120; }
        wtrans_lds(W, WTc1 + off, HID, N, (loc & 31) * 64, (loc >> 5) * 64, tb);
    } else {
        const int i = (id - 1152) * 256 + threadIdx.x;
        float4 v = *(const float4*)(x + (size_t)i * 4);
        uint32_t lo = (uint32_t)f2b(v.x) | ((uint32_t)f2b(v.y) << 16);
        uint32_t hi = (uint32_t)f2b(v.z) | ((uint32_t)f2b(v.w) << 16);
        *(uint2*)(xb + (size_t)i * 4) = make_uint2(lo, hi);
    }
}

// ============ prep2: qr-side + Wkv_b + Wo transposes (standalone, small LDS) =
// R11 post-mortem: merging these into the 64KB-LDS GEMM kernel (megaC1)
// dropped their occupancy 9->2 blocks/CU and serialized the latency-bound
// transposes (+40us). Split back out; LDS 16.9KB -> 9 blocks/CU TLP.
__global__ __launch_bounds__(256) void prep2(const float* __restrict__ W0,
                                             const float* __restrict__ W1,
                                             const float* __restrict__ Wkvb,
                                             const float* __restrict__ Wo,
                                             ushort* __restrict__ WT) {
    __shared__ float tb[64 * 65];
    const int id = blockIdx.x;
    const float* W; int K, N, nx; size_t off; int loc;
    if (id < 1152)      { W = W0;   K = QL;   N = 3072; nx = 24; off = 0;                 loc = id; }
    else if (id < 1344) { W = W1;   K = QL;   N = 512;  nx = 24; off = (size_t)3072 * QL; loc = id - 1152; }
    else if (id < 1856) { W = Wkvb; K = KVL;  N = 4096; nx = 8;  off = WT_OFF3;           loc = id - 1344; }
    else                { W = Wo;   K = 2048; N = 2048; nx = 32; off = WT_OFF4;           loc = id - 1856; }
    wtrans_lds(W, WT + off, K, N, (loc % nx) * 64, (loc / nx) * 64, tb);
}

// ============ generic single-GEMM launcher (f32 out) =========================
__global__ __launch_bounds__(256) void gemm_f32(const ushort* __restrict__ A,
                                                const ushort* __restrict__ BT,
                                                float* __restrict__ C,
                                                int N, int K) {
    __shared__ ushort As[2][8192];
    __shared__ ushort Bs[2][8192];
    gemm_tile<0>(A, BT, C, N, K, blockIdx.y * 128, blockIdx.x * 128,
                 &As[0][0], &Bs[0][0]);
}

// ============ megaC2: C2 GEMM (448) + kvexp GEMM (512) in one launch =========
// Both GEMMs (same 64KB LDS, occupancy-compatible): merged grid 960 blocks =
// 3.75/CU vs 1.75 + 2.0 serial.
__global__ __launch_bounds__(256) void megaC2(const ushort* __restrict__ qrb,
                                              const ushort* __restrict__ kvnb,
                                              const ushort* __restrict__ WT,
                                              float* __restrict__ C2,
                                              ushort* __restrict__ kvexp_h) {
    __shared__ ushort As[2][8192];
    __shared__ ushort Bs[2][8192];
    const int id = blockIdx.x;
    if (id < 448) {
        gemm_tile<0>(qrb, WT, C2, N2, QL, (id / 28) * 128, (id % 28) * 128,
                     &As[0][0], &Bs[0][0]);
    } else {
        const int loc = id - 448;
        gemm_tile<1>(kvnb, WT + WT_OFF3, kvexp_h, 4096, KVL,
                     (loc / 32) * 128, (loc % 32) * 128, &As[0][0], &Bs[0][0]);
    }
}

// ============ fused post-C1: rmsnorm(qr), rmsnorm(kv), rope(kpe), LN+rope(ki)+T
__global__ __launch_bounds__(256) void post_c1(const float* __restrict__ C1,
                                               const float* __restrict__ qw,
                                               const float* __restrict__ kvw,
                                               const float* __restrict__ ikg,
                                               const float* __restrict__ ikb,
                                               const float* __restrict__ cosb,
                                               const float* __restrict__ sinb,
                                               ushort* __restrict__ qrb,
                                               ushort* __restrict__ kvnb,
                                               float* __restrict__ kpe,
                                               float* __restrict__ kiT) {
    const int t = blockIdx.x, tid = threadIdx.x;
    const float* row = C1 + (size_t)t * N1;
    __shared__ float red[256];
    __shared__ float kis[128];
    float ss = 0.f;
    for (int i = tid; i < 1536; i += 256) { float v = row[i]; ss += v * v; }
    red[tid] = ss; __syncthreads();
    for (int st = 128; st > 0; st >>= 1) { if (tid < st) red[tid] += red[tid + st]; __syncthreads(); }
    float sq = rsqrtf(red[0] / 1536.f + 1e-6f);
    __syncthreads();
    float s2 = 0.f;
    for (int i = tid; i < 512; i += 256) { float v = row[1536 + i]; s2 += v * v; }
    red[tid] = s2; __syncthreads();
    for (int st = 128; st > 0; st >>= 1) { if (tid < st) red[tid] += red[tid + st]; __syncthreads(); }
    float skv = rsqrtf(red[0] / 512.f + 1e-6f);
    __syncthreads();
    float kv_ = (tid < 128) ? row[2112 + tid] : 0.f;
    red[tid] = kv_; __syncthreads();
    for (int st = 128; st > 0; st >>= 1) { if (tid < st) red[tid] += red[tid + st]; __syncthreads(); }
    float mu = red[0] / 128.f;
    __syncthreads();
    red[tid] = kv_ * kv_; __syncthreads();
    for (int st = 128; st > 0; st >>= 1) { if (tid < st) red[tid] += red[tid + st]; __syncthreads(); }
    float var = red[0] / 128.f - mu * mu;
    for (int i = tid; i < 1536; i += 256) qrb[(size_t)t * QL + i] = f2b(row[i] * sq * qw[i]);
    for (int i = tid; i < 512; i += 256)  kvnb[(size_t)t * KVL + i] = f2b(row[1536 + i] * skv * kvw[i]);
    if (tid < 32) {
        float c = cosb[t * 32 + tid], s = sinb[t * 32 + tid];
        float xr = row[2048 + 2 * tid], xi = row[2048 + 2 * tid + 1];
        kpe[t * 64 + 2 * tid]     = xr * c - xi * s;
        kpe[t * 64 + 2 * tid + 1] = xr * s + xi * c;
    }
    if (tid < 128) kis[tid] = (kv_ - mu) * rsqrtf(var + 1e-6f) * ikg[tid] + ikb[tid];
    __syncthreads();
    if (tid < 128) {
        float outv;
        if (tid < 32) {
            float c = cosb[t * 32 + tid], s = sinb[t * 32 + tid];
            outv = kis[tid] * c - kis[tid + 32] * s;
        } else if (tid < 64) {
            int j = tid - 32;
            float c = cosb[t * 32 + j], s = sinb[t * 32 + j];
            outv = kis[j] * s + kis[tid] * c;
        } else {
            outv = kis[tid];
        }
        kiT[(size_t)tid * S + t] = outv;
    }
}

// ============ megaPost: post_c2 (2048) + pack_kv (512) in one launch =========
__global__ __launch_bounds__(256) void megaPost(float* __restrict__ C2,
                                                const float* __restrict__ cosb,
                                                const float* __restrict__ sinb,
                                                ushort* __restrict__ qb,
                                                const ushort* __restrict__ kvexp_h,
                                                const float* __restrict__ kpe,
                                                ushort* __restrict__ kb,
                                                ushort* __restrict__ vT) {
    __shared__ float cs[32], sn[32];
    __shared__ ushort tt[64][136];
    const int id = blockIdx.x, tid = threadIdx.x;
    if (id < 2048) {
        const int t = id;
        if (tid < 32) { cs[tid] = cosb[t * 32 + tid]; sn[tid] = sinb[t * 32 + tid]; }
        __syncthreads();
        const float sc = 0.10412775370051047f;  // 192^-0.5 * log2(e)
        const float* src0 = C2 + (size_t)t * N2;
        for (int i = tid; i < NH * 96; i += 256) {
            int h = i / 96, p = i % 96;
            const float* src = src0 + h * 192;
            ushort* dst = qb + ((size_t)h * S + t) * 192;
            if (p < 64) {
                dst[2 * p]     = f2b(src[2 * p] * sc);
                dst[2 * p + 1] = f2b(src[2 * p + 1] * sc);
            } else {
                int j = p - 64;
                float c = cs[j], s = sn[j];
                float xr = src[128 + 2 * j], xi = src[128 + 2 * j + 1];
                dst[128 + 2 * j]     = f2b((xr * c - xi * s) * sc);
                dst[128 + 2 * j + 1] = f2b((xr * s + xi * c) * sc);
            }
        }
        if (tid < 128) {
            int h = tid >> 5, j = tid & 31;
            float* p = C2 + (size_t)t * N2 + 3072 + h * 128;
            float c = cs[j], s = sn[j];
            float x1 = p[j], x2 = p[j + 32];
            p[j] = x1 * c - x2 * s;
            p[j + 32] = x1 * s + x2 * c;
        }
    } else {
        const int loc = id - 2048;
        const int s0 = (loc & 31) * 64, h = loc >> 5;
        const int row = tid >> 2, c = tid & 3;
        const ushort* src = kvexp_h + (size_t)(s0 + row) * 4096 + h * 256;
        ushort* kbr = kb + ((size_t)h * S + s0 + row) * 192;
#pragma unroll
        for (int i = 0; i < 4; i++) {
            int off = c * 32 + i * 8;
            *(uint4*)(kbr + off) = *(const uint4*)(src + off);
            *(uint4*)(&tt[row][off]) = *(const uint4*)(src + 128 + off);
        }
        const float* kp = kpe + (size_t)(s0 + row) * 64 + c * 16;
#pragma unroll
        for (int i = 0; i < 16; i++) kbr[128 + c * 16 + i] = f2b(kp[i]);
        __syncthreads();
        const int d = tid >> 1, sh = (tid & 1) * 32;
        ushort* dst = vT + ((size_t)h * 128 + d) * S + s0 + sh;
#pragma unroll
        for (int i = 0; i < 32; i++) dst[i] = tt[sh + i][d];
    }
}

// ============ indexer score, 4 t-rows per block (verified R6) ================
__global__ __launch_bounds__(256) void iscore4x4(const float* __restrict__ qi,
                                                 const float* __restrict__ kiT,
                                                 const float* __restrict__ iw,
                                                 float* __restrict__ iscore) {
    const int t0 = blockIdx.x * 4;
    const int s0 = blockIdx.y * 1024;
    if (s0 > t0 + 3) return;
    const int s = s0 + threadIdx.x * 4;
    __shared__ float qsT[4 * ID * 4];   // [h][d][tt]
    __shared__ float ws[16];            // [tt][h]
    for (int i = threadIdx.x; i < 4 * ID * 4; i += 256) {
        int tt = i & 3, hd = i >> 2;
        qsT[hd * 4 + tt] = qi[(size_t)(t0 + tt) * N2 + hd];
    }
    if (threadIdx.x < 16) {
        int tt = threadIdx.x >> 2, h = threadIdx.x & 3;
        ws[threadIdx.x] = iw[(size_t)(t0 + tt) * N1 + h] * 0.04419417382415922f;
    }
    __syncthreads();
    if (s > t0 + 3) return;
    float a[4][4][4];                   // [tt][h][c]
#pragma unroll
    for (int tt = 0; tt < 4; tt++)
#pragma unroll
        for (int h = 0; h < 4; h++)
#pragma unroll
            for (int c = 0; c < 4; c++) a[tt][h][c] = 0.f;
    for (int d = 0; d < ID; d++) {
        float4 kv = *(const float4*)(kiT + (size_t)d * S + s);
#pragma unroll
        for (int h = 0; h < 4; h++) {
            float4 qv = *(const float4*)(&qsT[(h * ID + d) * 4]);  // .x..w = tt 0..3
            a[0][h][0] += qv.x * kv.x; a[0][h][1] += qv.x * kv.y;
            a[0][h][2] += qv.x * kv.z; a[0][h][3] += qv.x * kv.w;
            a[1][h][0] += qv.y * kv.x; a[1][h][1] += qv.y * kv.y;
            a[1][h][2] += qv.y * kv.z; a[1][h][3] += qv.y * kv.w;
            a[2][h][0] += qv.z * kv.x; a[2][h][1] += qv.z * kv.y;
            a[2][h][2] += qv.z * kv.z; a[2][h][3] += qv.z * kv.w;
            a[3][h][0] += qv.w * kv.x; a[3][h][1] += qv.w * kv.y;
            a[3][h][2] += qv.w * kv.z; a[3][h][3] += qv.w * kv.w;
        }
    }
#pragma unroll
    for (int tt = 0; tt < 4; tt++) {
        const int t = t0 + tt;
        if (s > t) continue;
#pragma unroll
        for (int c = 0; c < 4; c++) {
            if (s + c > t) break;
            float sc = fmaxf(a[tt][0][c], 0.f) * ws[tt * 4 + 0] +
                       fmaxf(a[tt][1][c], 0.f) * ws[tt * 4 + 1] +
                       fmaxf(a[tt][2][c], 0.f) * ws[tt * 4 + 2] +
                       fmaxf(a[tt][3][c], 0.f) * ws[tt * 4 + 3];
            iscore[(size_t)t * S + s + c] = sc;
        }
    }
}

// ============ exact top-k -> bitmask (verified R6 shfl-scan version) =========
__device__ inline unsigned sortable_u32(float f) {
    unsigned u = __float_as_uint(f);
    return (u & 0x80000000u) ? ~u : (u | 0x80000000u);
}

__global__ __launch_bounds__(256) void topk_mask(const float* __restrict__ iscore,
                                                 uint32_t* __restrict__ msk) {
    int t = blockIdx.x, tid = threadIdx.x;
    uint32_t* mrow = msk + (size_t)t * 64;
    if (t < TOPK) {
        if (tid < 64) {
            int full = (t + 1) >> 5;
            uint32_t wv2 = (tid < full) ? 0xFFFFFFFFu : 0u;
            if (tid == full) { int rem = (t + 1) & 31; wv2 = rem ? ((1u << rem) - 1u) : 0u; }
            mrow[tid] = wv2;
        }
        return;
    }
    const float* row = iscore + (size_t)t * S;
    const int n = t + 1;
    const int wv = tid >> 6, lane = tid & 63;
    __shared__ int hist[4][256];
    __shared__ int wtot[4];
    __shared__ int bsel, ksel;
    __shared__ uint32_t bytes[256];

    int jb = tid * 8;
    float4 v0 = *(const float4*)(row + jb);
    float4 v1 = *(const float4*)(row + jb + 4);
    uint32_t lsu[8];
    {
        float vvv[8] = {v0.x, v0.y, v0.z, v0.w, v1.x, v1.y, v1.z, v1.w};
#pragma unroll
        for (int i = 0; i < 8; i++)
            lsu[i] = (jb + i < n) ? sortable_u32(vvv[i]) : 0u;
    }
    unsigned prefix = 0, prefmask = 0;
    int k = TOPK;
    for (int pass = 0; pass < 4; pass++) {
        int shift = 24 - pass * 8;
#pragma unroll
        for (int r = 0; r < 4; r++) hist[r][tid] = 0;
        __syncthreads();
#pragma unroll
        for (int i = 0; i < 8; i++) {
            uint32_t u = lsu[i];
            if ((u & prefmask) == prefix) atomicAdd(&hist[wv][(u >> shift) & 255], 1);
        }
        __syncthreads();
        int h = hist[0][tid] + hist[1][tid] + hist[2][tid] + hist[3][tid];
        // inclusive suffix sum over the 256 buckets: per-wave shfl + fixup
        int x = h;
#pragma unroll
        for (int off = 1; off < 64; off <<= 1) {
            int tmp = __shfl_down(x, off, 64);
            if (lane + off < 64) x += tmp;
        }
        if (lane == 0) wtot[wv] = x;           // wave total = suffix at lane 0
        __syncthreads();
        int add = 0;
#pragma unroll
        for (int w2 = 1; w2 < 4; w2++) if (w2 > wv) add += wtot[w2];
        x += add;                               // suffix over buckets tid..255
        int snext = x - h;                      // = suffix at tid+1 (0 at 255)
        if (x >= k && snext < k) { bsel = tid; ksel = k - snext; }
        __syncthreads();
        prefix |= ((unsigned)bsel) << shift;
        prefmask |= 0xFFu << shift;
        k = ksel;
        __syncthreads();
    }
    const unsigned u_thr = prefix;
    const int need = k;
    uint32_t gtbits = 0, eqbits = 0;
    int eqcnt = 0;
#pragma unroll
    for (int i = 0; i < 8; i++) {
        uint32_t u = lsu[i];
        if (u > u_thr) gtbits |= 1u << i;
        else if (u == u_thr) { eqbits |= 1u << i; eqcnt++; }
    }
    // inclusive prefix sum of eqcnt: per-wave shfl_up + fixup
    {
        int x = eqcnt;
#pragma unroll
        for (int off = 1; off < 64; off <<= 1) {
            int tmp = __shfl_up(x, off, 64);
            if (lane >= off) x += tmp;
        }
        if (lane == 63) wtot[wv] = x;          // wave total = prefix at lane 63
        __syncthreads();
        int add = 0;
#pragma unroll
        for (int w2 = 0; w2 < 3; w2++) if (w2 < wv) add += wtot[w2];
        x += add;                               // inclusive prefix over 256
        int room = need - (x - eqcnt);
        uint32_t keep = 0;
#pragma unroll
        for (int i = 0; i < 8; i++)
            if ((eqbits >> i) & 1u) { if (room > 0) { keep |= 1u << i; room--; } }
        bytes[tid] = gtbits | keep;
    }
    __syncthreads();
    if (tid < 64)
        mrow[tid] = bytes[tid * 4] | (bytes[tid * 4 + 1] << 8) |
                    (bytes[tid * 4 + 2] << 16) | (bytes[tid * 4 + 3] << 24);
}

// ============ split-K flash attention v10 (R7/R10-best ~81us — frozen) =======
__global__ __launch_bounds__(256, 2) void fattn10(const ushort* __restrict__ qb,
                                                  const ushort* __restrict__ kb,
                                                  const ushort* __restrict__ vT,
                                                  const uint32_t* __restrict__ msk,
                                                  float* __restrict__ Opart,
                                                  float* __restrict__ mlbuf) {
    __shared__ ushort Ks[24 * 512];   // 24 KB
    __shared__ ushort Vs[16 * 512];   // 16 KB
    __shared__ ushort Pm[4][16 * 72]; // 9 KB
    const int tid = threadIdx.x;
    const int w = tid >> 6, l = tid & 63, quad = l >> 4, lane = l & 15;
    const int b = blockIdx.x;
    const int r8 = b & 7, j = b >> 3;
    const int h = r8 + 8 * (j & 1);
    const int idx = j >> 1;
    const int pair = idx & 15, part = idx >> 4;
    const int ta = pair, tb = 31 - pair, nA = ta + 1;
    const int vlo = part * 11, vhi = vlo + 11;
    const int qa0 = ta * 64, qb0 = tb * 64;

    bf16x8 qfa[6], qfb[6];
    {
        const ushort* qpa = qb + ((size_t)h * S + qa0 + w * 16 + lane) * 192;
        const ushort* qpb = qb + ((size_t)h * S + qb0 + w * 16 + lane) * 192;
#pragma unroll
        for (int ks = 0; ks < 6; ks++) {
            qfa[ks] = *(const bf16x8*)(qpa + ks * 32 + quad * 8);
            qfb[ks] = *(const bf16x8*)(qpb + ks * 32 + quad * 8);
        }
    }
    f32x4 oa[8], ob[8];
#pragma unroll
    for (int i = 0; i < 8; i++) { oa[i] = (f32x4)0.f; ob[i] = (f32x4)0.f; }
    float la[4], lb[4];
#pragma unroll
    for (int r = 0; r < 4; r++) { la[r] = 0.f; lb[r] = 0.f; }

    ushort* pw = &Pm[w][0];
    const ushort* kbase = kb + (size_t)h * S * 192;
    const ushort* vbase = vT + (size_t)h * 128 * S;

    for (int kt = 0; kt <= tb; kt++) {
        const int idxB = (kt <= ta) ? 2 * kt : kt + nA;
        const int hasA = (kt <= ta);
        const int idxA = 2 * kt + 1;
        const bool doB = (idxB >= vlo && idxB < vhi);
        const bool doA = hasA && (idxA >= vlo && idxA < vhi);
        if (!(doA || doB)) continue;           // block-uniform
        const int s0 = kt * 64;
        __syncthreads();
        // ---- DMA K: 24 issues (6/wave). issue i: ks=i>>2, kq=i&3; lane: quad,r15
#pragma unroll
        for (int ii = 0; ii < 6; ii++) {
            const int i = w * 6 + ii;
            const int ks = i >> 2, kq = i & 3;
            const ushort* src = kbase + (size_t)(s0 + kq * 16 + lane) * 192 + ks * 32 + quad * 8;
            GLL16(src, Ks + i * 512 + l * 8);
        }
        // ---- DMA V: 16 issues (4/wave). issue i: k2=i>>3, nt=i&7; lane: quad,d15
#pragma unroll
        for (int ii = 0; ii < 4; ii++) {
            const int i = w * 4 + ii;
            const int k2 = i >> 3, nt = i & 7;
            const ushort* src = vbase + (size_t)(nt * 16 + lane) * S + s0 + k2 * 32 + quad * 8;
            GLL16(src, Vs + i * 512 + l * 8);
        }
        __syncthreads();   // drains DMA

#pragma unroll
        for (int pass = 0; pass < 2; pass++) {
            if (pass == 0 && !doA) continue;
            if (pass == 1 && !doB) continue;
            const bf16x8* qf = (pass == 0) ? qfa : qfb;
            f32x4* oacc      = (pass == 0) ? oa : ob;
            float* ll        = (pass == 0) ? la : lb;
            const int q0t    = (pass == 0) ? qa0 : qb0;

            // QK^T (scores in log2e domain)
            f32x4 sc[4];
#pragma unroll
            for (int kq = 0; kq < 4; kq++) {
                sc[kq] = (f32x4)0.f;
#pragma unroll
                for (int ks = 0; ks < 6; ks++) {
                    bf16x8 bfr = *(const bf16x8*)(Ks + (ks * 4 + kq) * 512 + quad * 128 + lane * 8);
                    sc[kq] = __builtin_amdgcn_mfma_f32_16x16x32_bf16(qf[ks], bfr, sc[kq], 0, 0, 0);
                }
            }
            // mask words
            uint32_t w0[4], w1[4];
            {
                const int rowbase = q0t + w * 16 + quad * 4;
#pragma unroll
                for (int r = 0; r < 4; r++) {
                    const uint32_t* mp = msk + (size_t)(rowbase + r) * 64 + (s0 >> 5);
                    w0[r] = mp[0]; w1[r] = mp[1];
                }
            }
            // max-free softmax body: e = exp2(v); masked v=-1e30 -> e = 0
#pragma unroll
            for (int kq = 0; kq < 4; kq++) {
                const int sh = (kq & 1) * 16 + lane;
#pragma unroll
                for (int r = 0; r < 4; r++) {
                    uint32_t word = (kq < 2) ? w0[r] : w1[r];
                    float v = ((word >> sh) & 1u) ? sc[kq][r] : -1e30f;
                    float e = exp2f(v);
                    ll[r] += e;                     // lane-local partial l
                    pw[(quad * 4 + r) * 72 + kq * 16 + lane] = f2b(e);
                }
            }

            bf16x8 pfr[2];
#pragma unroll
            for (int k2 = 0; k2 < 2; k2++)
                pfr[k2] = *(const bf16x8*)(pw + lane * 72 + k2 * 32 + quad * 8);
#pragma unroll
            for (int nt = 0; nt < 8; nt++) {
#pragma unroll
                for (int k2 = 0; k2 < 2; k2++) {
                    bf16x8 vfr = *(const bf16x8*)(Vs + ((k2 * 8 + nt) * 4 + quad) * 128 + lane * 8);
                    oacc[nt] = __builtin_amdgcn_mfma_f32_16x16x32_bf16(pfr[k2], vfr, oacc[nt], 0, 0, 0);
                }
            }
        }
    }
    // deferred cross-lane reduction of l (once per block; offs 1,2,4,8 stay
    // within each 16-lane group = the score-row's column owners)
#pragma unroll
    for (int off = 1; off < 16; off <<= 1)
#pragma unroll
        for (int r = 0; r < 4; r++) {
            la[r] += __shfl_xor(la[r], off, 64);
            lb[r] += __shfl_xor(lb[r], off, 64);
        }
    // epilogue: f32 partials (unnormalized O + m=0,l), 3 parts
#pragma unroll
    for (int pass = 0; pass < 2; pass++) {
        const f32x4* oacc = (pass == 0) ? oa : ob;
        const float* ll   = (pass == 0) ? la : lb;
        const int qt      = (pass == 0) ? ta : tb;
        float* Op = Opart + (size_t)((qt * 16 + h) * 3 + part) * (64 * 128);
        float* mlp = mlbuf + (size_t)((qt * 16 + h) * 3 + part) * 128;
#pragma unroll
        for (int nt = 0; nt < 8; nt++)
#pragma unroll
            for (int r = 0; r < 4; r++)
                Op[(w * 16 + quad * 4 + r) * 128 + nt * 16 + lane] = oacc[nt][r];
        if (lane == 0) {
#pragma unroll
            for (int r = 0; r < 4; r++) {
                mlp[(w * 16 + quad * 4 + r) * 2 + 0] = 0.f;
                mlp[(w * 16 + quad * 4 + r) * 2 + 1] = ll[r];
            }
        }
    }
}

// ============ combine 3 split-K partials -> attn_b bf16 ======================
__global__ __launch_bounds__(256) void attn_combine(const float* __restrict__ Opart,
                                                    const float* __restrict__ mlbuf,
                                                    ushort* __restrict__ attn_b) {
    const int qt = blockIdx.x, h = blockIdx.y, tid = threadIdx.x;
    const size_t base = ((size_t)qt * 16 + h) * 3;
    const float* Op0 = Opart + base * 8192;
    const float* Op1 = Op0 + 8192;
    const float* Op2 = Op1 + 8192;
    const float* ml0 = mlbuf + base * 128;
    const float* ml1 = ml0 + 128;
    const float* ml2 = ml1 + 128;
#pragma unroll
    for (int i = 0; i < 32; i++) {
        int id = tid + i * 256;
        int row = id >> 7, d = id & 127;
        float m0 = ml0[row * 2], l0 = ml0[row * 2 + 1];
        float m1 = ml1[row * 2], l1 = ml1[row * 2 + 1];
        float m2 = ml2[row * 2], l2 = ml2[row * 2 + 1];
        float m = fmaxf(fmaxf(m0, m1), m2);
        float e0 = exp2f(m0 - m), e1 = exp2f(m1 - m), e2 = exp2f(m2 - m);
        float linv = 1.f / (l0 * e0 + l1 * e1 + l2 * e2);
        float v = (Op0[id] * e0 + Op1[id] * e1 + Op2[id] * e2) * linv;
        attn_b[(size_t)(qt * 64 + row) * 2048 + h * 128 + d] = f2b(v);
    }
}

// ============ host ===========================================================
extern "C" void kernel_launch(void* const* d_in, const int* in_sizes, int n_in,
                              void* d_out, int out_size, void* d_ws, size_t ws_size,
                              hipStream_t stream) {
    const float* x        = (const float*)d_in[0];
    const float* cosb     = (const float*)d_in[1];
    const float* sinb     = (const float*)d_in[2];
    const float* Wq_a     = (const float*)d_in[4];
    const float* q_norm_w = (const float*)d_in[5];
    const float* Wq_b     = (const float*)d_in[6];
    const float* Wkv_a    = (const float*)d_in[7];
    const float* kv_norm_w= (const float*)d_in[8];
    const float* Wkv_b    = (const float*)d_in[9];
    const float* Wo       = (const float*)d_in[10];
    const float* IWq_b    = (const float*)d_in[11];
    const float* IWk      = (const float*)d_in[12];
    const float* Ik_norm_w= (const float*)d_in[13];
    const float* Ik_norm_b= (const float*)d_in[14];
    const float* IWproj   = (const float*)d_in[15];
    float* out = (float*)d_out;

    char* ws = (char*)d_ws;
    size_t o = 0;
    auto take = [&](size_t b) { char* p = ws + o; o += (b + 255) & ~(size_t)255; return p; };
    ushort* xb     = (ushort*)take((size_t)S * HID * 2);
    ushort* qrb    = (ushort*)take((size_t)S * QL * 2);
    ushort* qb     = (ushort*)take((size_t)NH * S * DQ * 2);
    ushort* kvnb   = (ushort*)take((size_t)S * KVL * 2);
    float*  kpe    = (float*)take((size_t)S * DR * 4);
    ushort* kb     = (ushort*)take((size_t)NH * S * DQ * 2);
    ushort* vT     = (ushort*)take((size_t)NH * DV * S * 2);
    uint32_t* msk  = (uint32_t*)take((size_t)S * 64 * 4);
    float*  mlbuf  = (float*)take((size_t)32 * 16 * 3 * 64 * 2 * 4);
    ushort* WTp    = (ushort*)take(WT_TOTAL * 2);                   // c2 | Wkv_b^T | Wo^T | c1
    float*  C1     = (float*)take((size_t)S * N1 * 4);
    char*   big    = take((size_t)32 * 16 * 3 * 8192 * 4 + 1024);   // C2 f32 then Opart
    ushort* kvexp_h= (ushort*)take((size_t)S * 4096 * 2);
    float*  kiT    = (float*)take((size_t)128 * S * 4);
    char*   poolb  = take((size_t)16777216);                        // iscore / attn_b

    float* C2     = (float*)big;              // [S][N2] (qi consumed by iscore)
    float* Opart  = (float*)big;              // [32][16][3][64][128] f32
    float* iscore = (float*)poolb;
    ushort* attn_b = (ushort*)poolb;          // after topk consumed iscore

    // --- prep1: x->bf16 + c1-region weight transposes (one launch)
    prep1<<<5248, 256, 0, stream>>>(x, xb, Wq_a, Wkv_a, IWk, IWproj, WTp + WT_OFF5);

    // --- C1 GEMM (standalone, 64KB LDS) ; prep2 transposes (standalone, 17KB)
    gemm_f32<<<dim3(CDIV(N1, 128), S / 128), 256, 0, stream>>>(xb, WTp + WT_OFF5, C1, N1, HID);
    prep2<<<2880, 256, 0, stream>>>(Wq_b, IWq_b, Wkv_b, Wo, WTp);
    post_c1<<<S, 256, 0, stream>>>(C1, q_norm_w, kv_norm_w, Ik_norm_w, Ik_norm_b,
                                   cosb, sinb, qrb, kvnb, kpe, kiT);

    // --- megaC2: C2 GEMM + kvexp GEMM (one launch)
    megaC2<<<960, 256, 0, stream>>>(qrb, kvnb, WTp, C2, kvexp_h);

    // --- megaPost: post_c2 + pack_kv (one launch)
    megaPost<<<2560, 256, 0, stream>>>(C2, cosb, sinb, qb, kvexp_h, kpe, kb, vT);

    // --- indexer scores + exact top-k -> bitmap
    iscore4x4<<<dim3(S / 4, S / 1024), 256, 0, stream>>>(C2 + 3072, kiT, C1 + 2240, iscore);
    topk_mask<<<S, 256, 0, stream>>>(iscore, msk);

    // --- split-K masked flash attention (3 parts) + combine
    fattn10<<<768, 256, 0, stream>>>(qb, kb, vT, msk, Opart, mlbuf);
    attn_combine<<<dim3(32, 16), 256, 0, stream>>>(Opart, mlbuf, attn_b);

    // --- out = attn @ Wo
    gemm_f32<<<dim3(HID / 128, S / 128), 256, 0, stream>>>(attn_b, WTp + WT_OFF4, out, HID, NH * DV);

    (void)in_sizes; (void)n_in; (void)out_size; (void)ws_size; (void)o;
}

// Round 13
// 454.196 us; speedup vs baseline: 1.0657x; 1.0187x over previous
//
#include <hip/hip_runtime.h>
#include <math.h>
#include <stdint.h>

#define S 2048
#define HID 2048
#define NH 16
#define QL 1536
#define KVL 512
#define DN 128
#define DR 64
#define DV 128
#define DQ 192
#define IH 4
#define ID 128
#define TOPK 1024

#define N1 2244   // Wq_a(1536) | Wkv_a(576) | IWk(128) | IWproj(4)
#define N2 3584   // Wq_b(3072) | IWq_b(512)

// WTp sub-buffers (ushort elems): c2 Wq_b|IWq_b | Wkv_b^T | Wo^T | c1 block
#define WT_OFF3 ((size_t)N2 * QL)                    // 5505024
#define WT_OFF4 (WT_OFF3 + (size_t)4096 * KVL)       // 7602176
#define WT_OFF5 (WT_OFF4 + (size_t)2048 * 2048)      // 11796480
#define WT_TOTAL (WT_OFF5 + (size_t)N1 * HID)        // 16392192

#define CDIV(a,b) (((a)+(b)-1)/(b))

typedef float f32x4 __attribute__((ext_vector_type(4)));
typedef short bf16x8 __attribute__((ext_vector_type(8)));

__device__ __forceinline__ ushort f2b(float f) {
    uint32_t u = __float_as_uint(f);
    u += 0x7fffu + ((u >> 16) & 1u);
    return (ushort)(u >> 16);
}

#define GLL16(g, l)                                                            \
    __builtin_amdgcn_global_load_lds(                                          \
        (const __attribute__((address_space(1))) void*)(g),                    \
        (__attribute__((address_space(3))) void*)(l), 16, 0, 0)

// ============ GEMM tile body (R5/R7-proven structure, LDS passed in) =========
// 2-phase dbuf + BK=64 + rule-#21 swizzle. As/Bs: each 2*8192 ushorts (32KB).
// HALF=1 -> bf16 output.
#define STG64T(k0, s)                                                          \
    {                                                                          \
        _Pragma("unroll")                                                      \
        for (int p = 0; p < 4; p++) {                                          \
            GLL16(pA[p] + (k0), As + (s) * 8192 + p * 2048 + doff);            \
            GLL16(pB[p] + (k0), Bs + (s) * 8192 + p * 2048 + doff);            \
        }                                                                      \
    }

template<int HALF>
__device__ __forceinline__ void gemm_tile(const ushort* __restrict__ A,
                                          const ushort* __restrict__ BT,
                                          void* __restrict__ Cv,
                                          int N, int K, int row0, int col0,
                                          ushort* As, ushort* Bs) {
    const int tid = threadIdx.x;
    const int w = tid >> 6, l = tid & 63;
    const int quad = l >> 4, lane = l & 15;
    const int wr = (w >> 1) * 64, wc = (w & 1) * 64;
    f32x4 acc[4][4];
#pragma unroll
    for (int i = 0; i < 4; i++)
#pragma unroll
        for (int j = 0; j < 4; j++) acc[i][j] = (f32x4)0.f;

    const int r32 = tid >> 3;                              // 0..31
    const int csw = (((tid & 7) ^ (r32 & 7)) * 8);         // ushort offset
    const ushort* pA[4];
    const ushort* pB[4];
#pragma unroll
    for (int p = 0; p < 4; p++) {
        pA[p] = A + (size_t)(row0 + p * 32 + r32) * K + csw;
        int bn = col0 + p * 32 + r32; if (bn > N - 1) bn = N - 1;
        pB[p] = BT + (size_t)bn * K + csw;
    }
    const int doff = r32 * 64 + (tid & 7) * 8;             // linear LDS dst

    const int nt = K >> 6;
    STG64T(0, 0);
    asm volatile("s_waitcnt vmcnt(0)" ::: "memory");
    __builtin_amdgcn_s_barrier();

    const int xsw = (lane & 7) << 3;                       // read-side XOR
    int cur = 0;
    for (int t = 0; t < nt; ++t) {
        if (t + 1 < nt) STG64T((t + 1) * 64, cur ^ 1);
#pragma unroll
        for (int kk = 0; kk < 2; kk++) {
            const int fo = (kk * 32 + quad * 8) ^ xsw;
            bf16x8 af[4], bf[4];
#pragma unroll
            for (int mi = 0; mi < 4; mi++)
                af[mi] = *(const bf16x8*)(As + cur * 8192 + (wr + mi * 16 + lane) * 64 + fo);
#pragma unroll
            for (int ni = 0; ni < 4; ni++)
                bf[ni] = *(const bf16x8*)(Bs + cur * 8192 + (wc + ni * 16 + lane) * 64 + fo);
#pragma unroll
            for (int mi = 0; mi < 4; mi++)
#pragma unroll
                for (int ni = 0; ni < 4; ni++)
                    acc[mi][ni] = __builtin_amdgcn_mfma_f32_16x16x32_bf16(af[mi], bf[ni], acc[mi][ni], 0, 0, 0);
        }
        asm volatile("s_waitcnt vmcnt(0)" ::: "memory");
        __builtin_amdgcn_s_barrier();
        cur ^= 1;
    }
#pragma unroll
    for (int mi = 0; mi < 4; mi++)
#pragma unroll
        for (int ni = 0; ni < 4; ni++)
#pragma unroll
            for (int r = 0; r < 4; r++) {
                int row = row0 + wr + mi * 16 + quad * 4 + r;
                int col = col0 + wc + ni * 16 + lane;
                if (col < N) {
                    if (HALF) ((ushort*)Cv)[(size_t)row * N + col] = f2b(acc[mi][ni][r]);
                    else      ((float*)Cv)[(size_t)row * N + col] = acc[mi][ni][r];
                }
            }
}

// ============ transpose body (LDS passed in; t = 64x65 f32 region) ===========
__device__ __forceinline__ void wtrans_lds(const float* W, ushort* WT, int K, int N,
                                           int k0, int n0, float* t) {
    int rr = threadIdx.x >> 6, cc = threadIdx.x & 63;
#pragma unroll
    for (int p = 0; p < 16; p++) {
        int k = k0 + p * 4 + rr, n = n0 + cc;
        t[(p * 4 + rr) * 65 + cc] = (k < K && n < N) ? W[(size_t)k * N + n] : 0.f;
    }
    __syncthreads();
#pragma unroll
    for (int p = 0; p < 16; p++) {
        int n = n0 + p * 4 + rr, k = k0 + cc;
        if (n < N && k < K) WT[(size_t)n * K + k] = f2b(t[cc * 65 + p * 4 + rr]);
    }
}

// ============ prepAll: x->bf16 + ALL weight transposes (one launch) ==========
// R12: prep2 sat on the critical path (gemmC1 -> prep2 -> post_c1) though its
// outputs are only needed by megaC2. prep1+prep2 are occupancy-identical
// (16.9KB LDS, latency-bound, R11 lesson) -> merged; prep2's ~11us serial
// slot vanishes. ids: 0..1151 c1 transposes; 1152..5247 cvt; 5248..8127
// c2/Wkv_b/Wo transposes.
__global__ __launch_bounds__(256) void prepAll(const float* __restrict__ x,
                                               ushort* __restrict__ xb,
                                               const float* __restrict__ Wq_a,
                                               const float* __restrict__ Wkv_a,
                                               const float* __restrict__ IWk,
                                               const float* __restrict__ IWproj,
                                               const float* __restrict__ Wq_b,
                                               const float* __restrict__ IWq_b,
                                               const float* __restrict__ Wkvb,
                                               const float* __restrict__ Wo,
                                               ushort* __restrict__ WT) {
    __shared__ float tb[64 * 65];
    const int id = blockIdx.x;
    if (id < 1152) {
        const float* W; int N; size_t off; int loc;
        if (id < 768)       { W = Wq_a;   N = 1536; off = 0;                  loc = id; }
        else if (id < 1056) { W = Wkv_a;  N = 576;  off = (size_t)1536 * HID; loc = id - 768; }
        else if (id < 1120) { W = IWk;    N = 128;  off = (size_t)2112 * HID; loc = id - 1056; }
        else                { W = IWproj; N = 4;    off = (size_t)2240 * HID; loc = id - 1120; }
        wtrans_lds(W, WT + WT_OFF5 + off, HID, N, (loc & 31) * 64, (loc >> 5) * 64, tb);
    } else if (id < 5248) {
        const int i = (id - 1152) * 256 + threadIdx.x;
        float4 v = *(const float4*)(x + (size_t)i * 4);
        uint32_t lo = (uint32_t)f2b(v.x) | ((uint32_t)f2b(v.y) << 16);
        uint32_t hi = (uint32_t)f2b(v.z) | ((uint32_t)f2b(v.w) << 16);
        *(uint2*)(xb + (size_t)i * 4) = make_uint2(lo, hi);
    } else {
        const int pid = id - 5248;
        const float* W; int K, N, nx; size_t off; int loc;
        if (pid < 1152)      { W = Wq_b;  K = QL;   N = 3072; nx = 24; off = 0;                 loc = pid; }
        else if (pid < 1344) { W = IWq_b; K = QL;   N = 512;  nx = 24; off = (size_t)3072 * QL; loc = pid - 1152; }
        else if (pid < 1856) { W = Wkvb;  K = KVL;  N = 4096; nx = 8;  off = WT_OFF3;           loc = pid - 1344; }
        else                 { W = Wo;    K = 2048; N = 2048; nx = 32; off = WT_OFF4;           loc = pid - 1856; }
        wtrans_lds(W, WT + off, K, N, (loc % nx) * 64, (loc / nx) * 64, tb);
    }
}

// ============ generic single-GEMM launcher (f32 out) =========================
__global__ __launch_bounds__(256) void gemm_f32(const ushort* __restrict__ A,
                                                const ushort* __restrict__ BT,
                                                float* __restrict__ C,
                                                int N, int K) {
    __shared__ ushort As[2][8192];
    __shared__ ushort Bs[2][8192];
    gemm_tile<0>(A, BT, C, N, K, blockIdx.y * 128, blockIdx.x * 128,
                 &As[0][0], &Bs[0][0]);
}

// ============ megaC2: C2 GEMM (448) + kvexp GEMM (512) in one launch =========
// Both GEMMs (same 64KB LDS, occupancy-compatible): merged grid 960 blocks.
__global__ __launch_bounds__(256) void megaC2(const ushort* __restrict__ qrb,
                                              const ushort* __restrict__ kvnb,
                                              const ushort* __restrict__ WT,
                                              float* __restrict__ C2,
                                              ushort* __restrict__ kvexp_h) {
    __shared__ ushort As[2][8192];
    __shared__ ushort Bs[2][8192];
    const int id = blockIdx.x;
    if (id < 448) {
        gemm_tile<0>(qrb, WT, C2, N2, QL, (id / 28) * 128, (id % 28) * 128,
                     &As[0][0], &Bs[0][0]);
    } else {
        const int loc = id - 448;
        gemm_tile<1>(kvnb, WT + WT_OFF3, kvexp_h, 4096, KVL,
                     (loc / 32) * 128, (loc % 32) * 128, &As[0][0], &Bs[0][0]);
    }
}

// ============ fused post-C1: rmsnorm(qr), rmsnorm(kv), rope(kpe), LN+rope(ki)+T
__global__ __launch_bounds__(256) void post_c1(const float* __restrict__ C1,
                                               const float* __restrict__ qw,
                                               const float* __restrict__ kvw,
                                               const float* __restrict__ ikg,
                                               const float* __restrict__ ikb,
                                               const float* __restrict__ cosb,
                                               const float* __restrict__ sinb,
                                               ushort* __restrict__ qrb,
                                               ushort* __restrict__ kvnb,
                                               float* __restrict__ kpe,
                                               float* __restrict__ kiT) {
    const int t = blockIdx.x, tid = threadIdx.x;
    const float* row = C1 + (size_t)t * N1;
    __shared__ float red[256];
    __shared__ float kis[128];
    float ss = 0.f;
    for (int i = tid; i < 1536; i += 256) { float v = row[i]; ss += v * v; }
    red[tid] = ss; __syncthreads();
    for (int st = 128; st > 0; st >>= 1) { if (tid < st) red[tid] += red[tid + st]; __syncthreads(); }
    float sq = rsqrtf(red[0] / 1536.f + 1e-6f);
    __syncthreads();
    float s2 = 0.f;
    for (int i = tid; i < 512; i += 256) { float v = row[1536 + i]; s2 += v * v; }
    red[tid] = s2; __syncthreads();
    for (int st = 128; st > 0; st >>= 1) { if (tid < st) red[tid] += red[tid + st]; __syncthreads(); }
    float skv = rsqrtf(red[0] / 512.f + 1e-6f);
    __syncthreads();
    float kv_ = (tid < 128) ? row[2112 + tid] : 0.f;
    red[tid] = kv_; __syncthreads();
    for (int st = 128; st > 0; st >>= 1) { if (tid < st) red[tid] += red[tid + st]; __syncthreads(); }
    float mu = red[0] / 128.f;
    __syncthreads();
    red[tid] = kv_ * kv_; __syncthreads();
    for (int st = 128; st > 0; st >>= 1) { if (tid < st) red[tid] += red[tid + st]; __syncthreads(); }
    float var = red[0] / 128.f - mu * mu;
    for (int i = tid; i < 1536; i += 256) qrb[(size_t)t * QL + i] = f2b(row[i] * sq * qw[i]);
    for (int i = tid; i < 512; i += 256)  kvnb[(size_t)t * KVL + i] = f2b(row[1536 + i] * skv * kvw[i]);
    if (tid < 32) {
        float c = cosb[t * 32 + tid], s = sinb[t * 32 + tid];
        float xr = row[2048 + 2 * tid], xi = row[2048 + 2 * tid + 1];
        kpe[t * 64 + 2 * tid]     = xr * c - xi * s;
        kpe[t * 64 + 2 * tid + 1] = xr * s + xi * c;
    }
    if (tid < 128) kis[tid] = (kv_ - mu) * rsqrtf(var + 1e-6f) * ikg[tid] + ikb[tid];
    __syncthreads();
    if (tid < 128) {
        float outv;
        if (tid < 32) {
            float c = cosb[t * 32 + tid], s = sinb[t * 32 + tid];
            outv = kis[tid] * c - kis[tid + 32] * s;
        } else if (tid < 64) {
            int j = tid - 32;
            float c = cosb[t * 32 + j], s = sinb[t * 32 + j];
            outv = kis[j] * s + kis[tid] * c;
        } else {
            outv = kis[tid];
        }
        kiT[(size_t)tid * S + t] = outv;
    }
}

// ============ megaPost: post_c2 (2048) + pack_kv (512) in one launch =========
__global__ __launch_bounds__(256) void megaPost(float* __restrict__ C2,
                                                const float* __restrict__ cosb,
                                                const float* __restrict__ sinb,
                                                ushort* __restrict__ qb,
                                                const ushort* __restrict__ kvexp_h,
                                                const float* __restrict__ kpe,
                                                ushort* __restrict__ kb,
                                                ushort* __restrict__ vT) {
    __shared__ float cs[32], sn[32];
    __shared__ ushort tt[64][136];
    const int id = blockIdx.x, tid = threadIdx.x;
    if (id < 2048) {
        const int t = id;
        if (tid < 32) { cs[tid] = cosb[t * 32 + tid]; sn[tid] = sinb[t * 32 + tid]; }
        __syncthreads();
        const float sc = 0.10412775370051047f;  // 192^-0.5 * log2(e)
        const float* src0 = C2 + (size_t)t * N2;
        for (int i = tid; i < NH * 96; i += 256) {
            int h = i / 96, p = i % 96;
            const float* src = src0 + h * 192;
            ushort* dst = qb + ((size_t)h * S + t) * 192;
            if (p < 64) {
                dst[2 * p]     = f2b(src[2 * p] * sc);
                dst[2 * p + 1] = f2b(src[2 * p + 1] * sc);
            } else {
                int j = p - 64;
                float c = cs[j], s = sn[j];
                float xr = src[128 + 2 * j], xi = src[128 + 2 * j + 1];
                dst[128 + 2 * j]     = f2b((xr * c - xi * s) * sc);
                dst[128 + 2 * j + 1] = f2b((xr * s + xi * c) * sc);
            }
        }
        if (tid < 128) {
            int h = tid >> 5, j = tid & 31;
            float* p = C2 + (size_t)t * N2 + 3072 + h * 128;
            float c = cs[j], s = sn[j];
            float x1 = p[j], x2 = p[j + 32];
            p[j] = x1 * c - x2 * s;
            p[j + 32] = x1 * s + x2 * c;
        }
    } else {
        const int loc = id - 2048;
        const int s0 = (loc & 31) * 64, h = loc >> 5;
        const int row = tid >> 2, c = tid & 3;
        const ushort* src = kvexp_h + (size_t)(s0 + row) * 4096 + h * 256;
        ushort* kbr = kb + ((size_t)h * S + s0 + row) * 192;
#pragma unroll
        for (int i = 0; i < 4; i++) {
            int off = c * 32 + i * 8;
            *(uint4*)(kbr + off) = *(const uint4*)(src + off);
            *(uint4*)(&tt[row][off]) = *(const uint4*)(src + 128 + off);
        }
        const float* kp = kpe + (size_t)(s0 + row) * 64 + c * 16;
#pragma unroll
        for (int i = 0; i < 16; i++) kbr[128 + c * 16 + i] = f2b(kp[i]);
        __syncthreads();
        const int d = tid >> 1, sh = (tid & 1) * 32;
        ushort* dst = vT + ((size_t)h * 128 + d) * S + s0 + sh;
#pragma unroll
        for (int i = 0; i < 32; i++) dst[i] = tt[sh + i][d];
    }
}

// ============ indexer score, 4 t-rows per block, rows >= TOPK only ===========
// R12: iscore is consumed only by topk_mask, which early-returns (trivial
// causal mask) for t < TOPK without reading the row. Rows 0..1023 (~25% of
// causal area + 256 full kiT slab reads) were dead work -> grid (256,2),
// t0 = 1024 + 4*bx. Output-identical.
__global__ __launch_bounds__(256) void iscore4x4(const float* __restrict__ qi,
                                                 const float* __restrict__ kiT,
                                                 const float* __restrict__ iw,
                                                 float* __restrict__ iscore) {
    const int t0 = TOPK + blockIdx.x * 4;
    const int s0 = blockIdx.y * 1024;
    const int s = s0 + threadIdx.x * 4;
    __shared__ float qsT[4 * ID * 4];   // [h][d][tt]
    __shared__ float ws[16];            // [tt][h]
    for (int i = threadIdx.x; i < 4 * ID * 4; i += 256) {
        int tt = i & 3, hd = i >> 2;
        qsT[hd * 4 + tt] = qi[(size_t)(t0 + tt) * N2 + hd];
    }
    if (threadIdx.x < 16) {
        int tt = threadIdx.x >> 2, h = threadIdx.x & 3;
        ws[threadIdx.x] = iw[(size_t)(t0 + tt) * N1 + h] * 0.04419417382415922f;
    }
    __syncthreads();
    if (s > t0 + 3) return;
    float a[4][4][4];                   // [tt][h][c]
#pragma unroll
    for (int tt = 0; tt < 4; tt++)
#pragma unroll
        for (int h = 0; h < 4; h++)
#pragma unroll
            for (int c = 0; c < 4; c++) a[tt][h][c] = 0.f;
    for (int d = 0; d < ID; d++) {
        float4 kv = *(const float4*)(kiT + (size_t)d * S + s);
#pragma unroll
        for (int h = 0; h < 4; h++) {
            float4 qv = *(const float4*)(&qsT[(h * ID + d) * 4]);  // .x..w = tt 0..3
            a[0][h][0] += qv.x * kv.x; a[0][h][1] += qv.x * kv.y;
            a[0][h][2] += qv.x * kv.z; a[0][h][3] += qv.x * kv.w;
            a[1][h][0] += qv.y * kv.x; a[1][h][1] += qv.y * kv.y;
            a[1][h][2] += qv.y * kv.z; a[1][h][3] += qv.y * kv.w;
            a[2][h][0] += qv.z * kv.x; a[2][h][1] += qv.z * kv.y;
            a[2][h][2] += qv.z * kv.z; a[2][h][3] += qv.z * kv.w;
            a[3][h][0] += qv.w * kv.x; a[3][h][1] += qv.w * kv.y;
            a[3][h][2] += qv.w * kv.z; a[3][h][3] += qv.w * kv.w;
        }
    }
#pragma unroll
    for (int tt = 0; tt < 4; tt++) {
        const int t = t0 + tt;
        if (s > t) continue;
#pragma unroll
        for (int c = 0; c < 4; c++) {
            if (s + c > t) break;
            float sc = fmaxf(a[tt][0][c], 0.f) * ws[tt * 4 + 0] +
                       fmaxf(a[tt][1][c], 0.f) * ws[tt * 4 + 1] +
                       fmaxf(a[tt][2][c], 0.f) * ws[tt * 4 + 2] +
                       fmaxf(a[tt][3][c], 0.f) * ws[tt * 4 + 3];
            iscore[(size_t)t * S + s + c] = sc;
        }
    }
}

// ============ exact top-k -> bitmask (verified R6 shfl-scan version) =========
__device__ inline unsigned sortable_u32(float f) {
    unsigned u = __float_as_uint(f);
    return (u & 0x80000000u) ? ~u : (u | 0x80000000u);
}

__global__ __launch_bounds__(256) void topk_mask(const float* __restrict__ iscore,
                                                 uint32_t* __restrict__ msk) {
    int t = blockIdx.x, tid = threadIdx.x;
    uint32_t* mrow = msk + (size_t)t * 64;
    if (t < TOPK) {
        if (tid < 64) {
            int full = (t + 1) >> 5;
            uint32_t wv2 = (tid < full) ? 0xFFFFFFFFu : 0u;
            if (tid == full) { int rem = (t + 1) & 31; wv2 = rem ? ((1u << rem) - 1u) : 0u; }
            mrow[tid] = wv2;
        }
        return;
    }
    const float* row = iscore + (size_t)t * S;
    const int n = t + 1;
    const int wv = tid >> 6, lane = tid & 63;
    __shared__ int hist[4][256];
    __shared__ int wtot[4];
    __shared__ int bsel, ksel;
    __shared__ uint32_t bytes[256];

    int jb = tid * 8;
    float4 v0 = *(const float4*)(row + jb);
    float4 v1 = *(const float4*)(row + jb + 4);
    uint32_t lsu[8];
    {
        float vvv[8] = {v0.x, v0.y, v0.z, v0.w, v1.x, v1.y, v1.z, v1.w};
#pragma unroll
        for (int i = 0; i < 8; i++)
            lsu[i] = (jb + i < n) ? sortable_u32(vvv[i]) : 0u;
    }
    unsigned prefix = 0, prefmask = 0;
    int k = TOPK;
    for (int pass = 0; pass < 4; pass++) {
        int shift = 24 - pass * 8;
#pragma unroll
        for (int r = 0; r < 4; r++) hist[r][tid] = 0;
        __syncthreads();
#pragma unroll
        for (int i = 0; i < 8; i++) {
            uint32_t u = lsu[i];
            if ((u & prefmask) == prefix) atomicAdd(&hist[wv][(u >> shift) & 255], 1);
        }
        __syncthreads();
        int h = hist[0][tid] + hist[1][tid] + hist[2][tid] + hist[3][tid];
        // inclusive suffix sum over the 256 buckets: per-wave shfl + fixup
        int x = h;
#pragma unroll
        for (int off = 1; off < 64; off <<= 1) {
            int tmp = __shfl_down(x, off, 64);
            if (lane + off < 64) x += tmp;
        }
        if (lane == 0) wtot[wv] = x;           // wave total = suffix at lane 0
        __syncthreads();
        int add = 0;
#pragma unroll
        for (int w2 = 1; w2 < 4; w2++) if (w2 > wv) add += wtot[w2];
        x += add;                               // suffix over buckets tid..255
        int snext = x - h;                      // = suffix at tid+1 (0 at 255)
        if (x >= k && snext < k) { bsel = tid; ksel = k - snext; }
        __syncthreads();
        prefix |= ((unsigned)bsel) << shift;
        prefmask |= 0xFFu << shift;
        k = ksel;
        __syncthreads();
    }
    const unsigned u_thr = prefix;
    const int need = k;
    uint32_t gtbits = 0, eqbits = 0;
    int eqcnt = 0;
#pragma unroll
    for (int i = 0; i < 8; i++) {
        uint32_t u = lsu[i];
        if (u > u_thr) gtbits |= 1u << i;
        else if (u == u_thr) { eqbits |= 1u << i; eqcnt++; }
    }
    // inclusive prefix sum of eqcnt: per-wave shfl_up + fixup
    {
        int x = eqcnt;
#pragma unroll
        for (int off = 1; off < 64; off <<= 1) {
            int tmp = __shfl_up(x, off, 64);
            if (lane >= off) x += tmp;
        }
        if (lane == 63) wtot[wv] = x;          // wave total = prefix at lane 63
        __syncthreads();
        int add = 0;
#pragma unroll
        for (int w2 = 0; w2 < 3; w2++) if (w2 < wv) add += wtot[w2];
        x += add;                               // inclusive prefix over 256
        int room = need - (x - eqcnt);
        uint32_t keep = 0;
#pragma unroll
        for (int i = 0; i < 8; i++)
            if ((eqbits >> i) & 1u) { if (room > 0) { keep |= 1u << i; room--; } }
        bytes[tid] = gtbits | keep;
    }
    __syncthreads();
    if (tid < 64)
        mrow[tid] = bytes[tid * 4] | (bytes[tid * 4 + 1] << 8) |
                    (bytes[tid * 4 + 2] << 16) | (bytes[tid * 4 + 3] << 24);
}

// ============ split-K flash attention v10 (R7/R10-best ~81us — frozen) =======
__global__ __launch_bounds__(256, 2) void fattn10(const ushort* __restrict__ qb,
                                                  const ushort* __restrict__ kb,
                                                  const ushort* __restrict__ vT,
                                                  const uint32_t* __restrict__ msk,
                                                  float* __restrict__ Opart,
                                                  float* __restrict__ mlbuf) {
    __shared__ ushort Ks[24 * 512];   // 24 KB
    __shared__ ushort Vs[16 * 512];   // 16 KB
    __shared__ ushort Pm[4][16 * 72]; // 9 KB
    const int tid = threadIdx.x;
    const int w = tid >> 6, l = tid & 63, quad = l >> 4, lane = l & 15;
    const int b = blockIdx.x;
    const int r8 = b & 7, j = b >> 3;
    const int h = r8 + 8 * (j & 1);
    const int idx = j >> 1;
    const int pair = idx & 15, part = idx >> 4;
    const int ta = pair, tb = 31 - pair, nA = ta + 1;
    const int vlo = part * 11, vhi = vlo + 11;
    const int qa0 = ta * 64, qb0 = tb * 64;

    bf16x8 qfa[6], qfb[6];
    {
        const ushort* qpa = qb + ((size_t)h * S + qa0 + w * 16 + lane) * 192;
        const ushort* qpb = qb + ((size_t)h * S + qb0 + w * 16 + lane) * 192;
#pragma unroll
        for (int ks = 0; ks < 6; ks++) {
            qfa[ks] = *(const bf16x8*)(qpa + ks * 32 + quad * 8);
            qfb[ks] = *(const bf16x8*)(qpb + ks * 32 + quad * 8);
        }
    }
    f32x4 oa[8], ob[8];
#pragma unroll
    for (int i = 0; i < 8; i++) { oa[i] = (f32x4)0.f; ob[i] = (f32x4)0.f; }
    float la[4], lb[4];
#pragma unroll
    for (int r = 0; r < 4; r++) { la[r] = 0.f; lb[r] = 0.f; }

    ushort* pw = &Pm[w][0];
    const ushort* kbase = kb + (size_t)h * S * 192;
    const ushort* vbase = vT + (size_t)h * 128 * S;

    for (int kt = 0; kt <= tb; kt++) {
        const int idxB = (kt <= ta) ? 2 * kt : kt + nA;
        const int hasA = (kt <= ta);
        const int idxA = 2 * kt + 1;
        const bool doB = (idxB >= vlo && idxB < vhi);
        const bool doA = hasA && (idxA >= vlo && idxA < vhi);
        if (!(doA || doB)) continue;           // block-uniform
        const int s0 = kt * 64;
        __syncthreads();
        // ---- DMA K: 24 issues (6/wave). issue i: ks=i>>2, kq=i&3; lane: quad,r15
#pragma unroll
        for (int ii = 0; ii < 6; ii++) {
            const int i = w * 6 + ii;
            const int ks = i >> 2, kq = i & 3;
            const ushort* src = kbase + (size_t)(s0 + kq * 16 + lane) * 192 + ks * 32 + quad * 8;
            GLL16(src, Ks + i * 512 + l * 8);
        }
        // ---- DMA V: 16 issues (4/wave). issue i: k2=i>>3, nt=i&7; lane: quad,d15
#pragma unroll
        for (int ii = 0; ii < 4; ii++) {
            const int i = w * 4 + ii;
            const int k2 = i >> 3, nt = i & 7;
            const ushort* src = vbase + (size_t)(nt * 16 + lane) * S + s0 + k2 * 32 + quad * 8;
            GLL16(src, Vs + i * 512 + l * 8);
        }
        __syncthreads();   // drains DMA

#pragma unroll
        for (int pass = 0; pass < 2; pass++) {
            if (pass == 0 && !doA) continue;
            if (pass == 1 && !doB) continue;
            const bf16x8* qf = (pass == 0) ? qfa : qfb;
            f32x4* oacc      = (pass == 0) ? oa : ob;
            float* ll        = (pass == 0) ? la : lb;
            const int q0t    = (pass == 0) ? qa0 : qb0;

            // QK^T (scores in log2e domain)
            f32x4 sc[4];
#pragma unroll
            for (int kq = 0; kq < 4; kq++) {
                sc[kq] = (f32x4)0.f;
#pragma unroll
                for (int ks = 0; ks < 6; ks++) {
                    bf16x8 bfr = *(const bf16x8*)(Ks + (ks * 4 + kq) * 512 + quad * 128 + lane * 8);
                    sc[kq] = __builtin_amdgcn_mfma_f32_16x16x32_bf16(qf[ks], bfr, sc[kq], 0, 0, 0);
                }
            }
            // mask words
            uint32_t w0[4], w1[4];
            {
                const int rowbase = q0t + w * 16 + quad * 4;
#pragma unroll
                for (int r = 0; r < 4; r++) {
                    const uint32_t* mp = msk + (size_t)(rowbase + r) * 64 + (s0 >> 5);
                    w0[r] = mp[0]; w1[r] = mp[1];
                }
            }
            // max-free softmax body: e = exp2(v); masked v=-1e30 -> e = 0
#pragma unroll
            for (int kq = 0; kq < 4; kq++) {
                const int sh = (kq & 1) * 16 + lane;
#pragma unroll
                for (int r = 0; r < 4; r++) {
                    uint32_t word = (kq < 2) ? w0[r] : w1[r];
                    float v = ((word >> sh) & 1u) ? sc[kq][r] : -1e30f;
                    float e = exp2f(v);
                    ll[r] += e;                     // lane-local partial l
                    pw[(quad * 4 + r) * 72 + kq * 16 + lane] = f2b(e);
                }
            }

            bf16x8 pfr[2];
#pragma unroll
            for (int k2 = 0; k2 < 2; k2++)
                pfr[k2] = *(const bf16x8*)(pw + lane * 72 + k2 * 32 + quad * 8);
#pragma unroll
            for (int nt = 0; nt < 8; nt++) {
#pragma unroll
                for (int k2 = 0; k2 < 2; k2++) {
                    bf16x8 vfr = *(const bf16x8*)(Vs + ((k2 * 8 + nt) * 4 + quad) * 128 + lane * 8);
                    oacc[nt] = __builtin_amdgcn_mfma_f32_16x16x32_bf16(pfr[k2], vfr, oacc[nt], 0, 0, 0);
                }
            }
        }
    }
    // deferred cross-lane reduction of l (once per block; offs 1,2,4,8 stay
    // within each 16-lane group = the score-row's column owners)
#pragma unroll
    for (int off = 1; off < 16; off <<= 1)
#pragma unroll
        for (int r = 0; r < 4; r++) {
            la[r] += __shfl_xor(la[r], off, 64);
            lb[r] += __shfl_xor(lb[r], off, 64);
        }
    // epilogue: f32 partials (unnormalized O + m=0,l), 3 parts
#pragma unroll
    for (int pass = 0; pass < 2; pass++) {
        const f32x4* oacc = (pass == 0) ? oa : ob;
        const float* ll   = (pass == 0) ? la : lb;
        const int qt      = (pass == 0) ? ta : tb;
        float* Op = Opart + (size_t)((qt * 16 + h) * 3 + part) * (64 * 128);
        float* mlp = mlbuf + (size_t)((qt * 16 + h) * 3 + part) * 128;
#pragma unroll
        for (int nt = 0; nt < 8; nt++)
#pragma unroll
            for (int r = 0; r < 4; r++)
                Op[(w * 16 + quad * 4 + r) * 128 + nt * 16 + lane] = oacc[nt][r];
        if (lane == 0) {
#pragma unroll
            for (int r = 0; r < 4; r++) {
                mlp[(w * 16 + quad * 4 + r) * 2 + 0] = 0.f;
                mlp[(w * 16 + quad * 4 + r) * 2 + 1] = ll[r];
            }
        }
    }
}

// ============ combine 3 split-K partials -> attn_b bf16 ======================
__global__ __launch_bounds__(256) void attn_combine(const float* __restrict__ Opart,
                                                    const float* __restrict__ mlbuf,
                                                    ushort* __restrict__ attn_b) {
    const int qt = blockIdx.x, h = blockIdx.y, tid = threadIdx.x;
    const size_t base = ((size_t)qt * 16 + h) * 3;
    const float* Op0 = Opart + base * 8192;
    const float* Op1 = Op0 + 8192;
    const float* Op2 = Op1 + 8192;
    const float* ml0 = mlbuf + base * 128;
    const float* ml1 = ml0 + 128;
    const float* ml2 = ml1 + 128;
#pragma unroll
    for (int i = 0; i < 32; i++) {
        int id = tid + i * 256;
        int row = id >> 7, d = id & 127;
        float m0 = ml0[row * 2], l0 = ml0[row * 2 + 1];
        float m1 = ml1[row * 2], l1 = ml1[row * 2 + 1];
        float m2 = ml2[row * 2], l2 = ml2[row * 2 + 1];
        float m = fmaxf(fmaxf(m0, m1), m2);
        float e0 = exp2f(m0 - m), e1 = exp2f(m1 - m), e2 = exp2f(m2 - m);
        float linv = 1.f / (l0 * e0 + l1 * e1 + l2 * e2);
        float v = (Op0[id] * e0 + Op1[id] * e1 + Op2[id] * e2) * linv;
        attn_b[(size_t)(qt * 64 + row) * 2048 + h * 128 + d] = f2b(v);
    }
}

// ============ host ===========================================================
extern "C" void kernel_launch(void* const* d_in, const int* in_sizes, int n_in,
                              void* d_out, int out_size, void* d_ws, size_t ws_size,
                              hipStream_t stream) {
    const float* x        = (const float*)d_in[0];
    const float* cosb     = (const float*)d_in[1];
    const float* sinb     = (const float*)d_in[2];
    const float* Wq_a     = (const float*)d_in[4];
    const float* q_norm_w = (const float*)d_in[5];
    const float* Wq_b     = (const float*)d_in[6];
    const float* Wkv_a    = (const float*)d_in[7];
    const float* kv_norm_w= (const float*)d_in[8];
    const float* Wkv_b    = (const float*)d_in[9];
    const float* Wo       = (const float*)d_in[10];
    const float* IWq_b    = (const float*)d_in[11];
    const float* IWk      = (const float*)d_in[12];
    const float* Ik_norm_w= (const float*)d_in[13];
    const float* Ik_norm_b= (const float*)d_in[14];
    const float* IWproj   = (const float*)d_in[15];
    float* out = (float*)d_out;

    char* ws = (char*)d_ws;
    size_t o = 0;
    auto take = [&](size_t b) { char* p = ws + o; o += (b + 255) & ~(size_t)255; return p; };
    ushort* xb     = (ushort*)take((size_t)S * HID * 2);
    ushort* qrb    = (ushort*)take((size_t)S * QL * 2);
    ushort* qb     = (ushort*)take((size_t)NH * S * DQ * 2);
    ushort* kvnb   = (ushort*)take((size_t)S * KVL * 2);
    float*  kpe    = (float*)take((size_t)S * DR * 4);
    ushort* kb     = (ushort*)take((size_t)NH * S * DQ * 2);
    ushort* vT     = (ushort*)take((size_t)NH * DV * S * 2);
    uint32_t* msk  = (uint32_t*)take((size_t)S * 64 * 4);
    float*  mlbuf  = (float*)take((size_t)32 * 16 * 3 * 64 * 2 * 4);
    ushort* WTp    = (ushort*)take(WT_TOTAL * 2);                   // c2 | Wkv_b^T | Wo^T | c1
    float*  C1     = (float*)take((size_t)S * N1 * 4);
    char*   big    = take((size_t)32 * 16 * 3 * 8192 * 4 + 1024);   // C2 f32 then Opart
    ushort* kvexp_h= (ushort*)take((size_t)S * 4096 * 2);
    float*  kiT    = (float*)take((size_t)128 * S * 4);
    char*   poolb  = take((size_t)16777216);                        // iscore / attn_b

    float* C2     = (float*)big;              // [S][N2] (qi consumed by iscore)
    float* Opart  = (float*)big;              // [32][16][3][64][128] f32
    float* iscore = (float*)poolb;
    ushort* attn_b = (ushort*)poolb;          // after topk consumed iscore

    // --- prepAll: x->bf16 + ALL weight transposes (one launch)
    prepAll<<<8128, 256, 0, stream>>>(x, xb, Wq_a, Wkv_a, IWk, IWproj,
                                      Wq_b, IWq_b, Wkv_b, Wo, WTp);

    // --- C1 GEMM -> post_c1
    gemm_f32<<<dim3(CDIV(N1, 128), S / 128), 256, 0, stream>>>(xb, WTp + WT_OFF5, C1, N1, HID);
    post_c1<<<S, 256, 0, stream>>>(C1, q_norm_w, kv_norm_w, Ik_norm_w, Ik_norm_b,
                                   cosb, sinb, qrb, kvnb, kpe, kiT);

    // --- megaC2: C2 GEMM + kvexp GEMM (one launch)
    megaC2<<<960, 256, 0, stream>>>(qrb, kvnb, WTp, C2, kvexp_h);

    // --- megaPost: post_c2 + pack_kv (one launch)
    megaPost<<<2560, 256, 0, stream>>>(C2, cosb, sinb, qb, kvexp_h, kpe, kb, vT);

    // --- indexer scores (rows >= TOPK only) + exact top-k -> bitmap
    iscore4x4<<<dim3(256, 2), 256, 0, stream>>>(C2 + 3072, kiT, C1 + 2240, iscore);
    topk_mask<<<S, 256, 0, stream>>>(iscore, msk);

    // --- split-K masked flash attention (3 parts) + combine
    fattn10<<<768, 256, 0, stream>>>(qb, kb, vT, msk, Opart, mlbuf);
    attn_combine<<<dim3(32, 16), 256, 0, stream>>>(Opart, mlbuf, attn_b);

    // --- out = attn @ Wo
    gemm_f32<<<dim3(HID / 128, S / 128), 256, 0, stream>>>(attn_b, WTp + WT_OFF4, out, HID, NH * DV);

    (void)in_sizes; (void)n_in; (void)out_size; (void)ws_size; (void)o;
}